// Round 5
// baseline (463.031 us; speedup 1.0000x reference)
//
#include <hip/hip_runtime.h>
#include <cstdint>
#include <cstddef>

#define DI static __device__ __forceinline__

using half_t  = _Float16;
using half2_t = __attribute__((ext_vector_type(2))) _Float16;
using half8_t = __attribute__((ext_vector_type(8))) _Float16;
using f32x4_t = __attribute__((ext_vector_type(4))) float;

DI uint32_t pack2(float a, float b){ half2_t h; h[0]=(half_t)a; h[1]=(half_t)b; return __builtin_bit_cast(uint32_t,h); }
DI uint16_t f16b(float a){ return __builtin_bit_cast(uint16_t,(half_t)a); }
DI float lo16(uint32_t u){ half2_t h=__builtin_bit_cast(half2_t,u); return (float)h[0]; }
DI float hi16(uint32_t u){ half2_t h=__builtin_bit_cast(half2_t,u); return (float)h[1]; }
DI float fdot2(uint32_t w, uint32_t x, float acc){
  return __builtin_amdgcn_fdot2(__builtin_bit_cast(half2_t,w), __builtin_bit_cast(half2_t,x), acc, false);
}
DI float sigm(float x){ return __builtin_amdgcn_rcpf(1.f + __expf(-x)); }
DI float tanhf_(float x){ return 1.f - 2.f*__builtin_amdgcn_rcpf(__expf(2.f*x)+1.f); }

// problem sizes: B=32 S=64 NW=2048 T=198 L=50 WLEN=20 BERT=178 Hs=128 Hm=256 Din=306 O=32
#define SROW 308   // sentences_in row stride (306 used)
#define HSTR 280   // k_srec h-row stride in halves

// prep job sizes
#define N0 32768   // word Whh MFMA-B frags [ng512][kp64]
#define N1 16384   // word Wih MFMA-B frags [ng512][kp32] (k=50 zero-padded to 64)
#define N2 8192    // Wl MFMA-B frags [d128][kp64]
#define N3 512     // word bias sum [j128][g4]
#define N4 262144  // sent Whh B-frag layout [dir][ng1024][kp128], ng=w*256+g*64+p*16+jl
#define N5 313344  // sent Wih f16x2 [dir][kp153][j256][g4]
#define N6 2048    // sent bias sum [dir][j256][g4]
#define N7 8192    // Wo f16x2 [kp256][o32]
#define N8 364544  // bert -> sent[:,128:306]
#define NTOT (N0+N1+N2+N3+N4+N5+N6+N7+N8)

__global__ void k_prep(const float* __restrict__ X,
                       const float* __restrict__ Wih_w, const float* __restrict__ Whh_w,
                       const float* __restrict__ bih_w, const float* __restrict__ bhh_w,
                       const float* __restrict__ Wl,
                       const float* __restrict__ Wih_f, const float* __restrict__ Whh_f,
                       const float* __restrict__ bih_f, const float* __restrict__ bhh_f,
                       const float* __restrict__ Wih_b, const float* __restrict__ Whh_b,
                       const float* __restrict__ bih_b, const float* __restrict__ bhh_b,
                       const float* __restrict__ Wo,
                       uint32_t* __restrict__ wWsw, uint32_t* __restrict__ wWxw,
                       uint32_t* __restrict__ wWlf, float* __restrict__ wbsw,
                       uint32_t* __restrict__ wWs, uint32_t* __restrict__ wWihs,
                       float* __restrict__ wbss, uint32_t* __restrict__ wWo,
                       float* __restrict__ sent)
{
  for (int i = blockIdx.x*blockDim.x + threadIdx.x; i < NTOT; i += gridDim.x*blockDim.x) {
    int id = i;
    if (id < N0) {                       // word Whh B-frags: ng = w*64+g*16+jl -> row g*128+w*16+jl
      int kp = id & 63, ng = id >> 6;
      int w = ng>>6, g = (ng>>4)&3, jl = ng&15;
      const float* s = Whh_w + (size_t)(g*128 + w*16 + jl)*128 + 2*kp;
      wWsw[id] = pack2(s[0], s[1]);
    } else if ((id -= N0) < N1) {        // word Wih B-frags, k padded 50->64
      int kp = id & 31, ng = id >> 5;
      int w = ng>>6, g = (ng>>4)&3, jl = ng&15;
      if (kp < 25) {
        const float* s = Wih_w + (size_t)(g*128 + w*16 + jl)*50 + 2*kp;
        wWxw[id] = pack2(s[0], s[1]);
      } else wWxw[id] = 0u;
    } else if ((id -= N1) < N2) {        // Wl B-frags [d][kp]
      int kp = id & 63, d = id >> 6;
      const float* s = Wl + (size_t)d*128 + 2*kp;
      wWlf[id] = pack2(s[0], s[1]);
    } else if ((id -= N2) < N3) {        // word bias sum [j][g]
      int g = id & 3, j = id>>2;
      wbsw[id] = bih_w[g*128+j] + bhh_w[g*128+j];
    } else if ((id -= N3) < N4) {        // sentence Whh: ng = w*256 + g*64 + p*16 + jl
      int kp = id & 127, ng = (id>>7)&1023, dir = id>>17;
      int w = (ng>>8)&3, g = (ng>>6)&3, p = (ng>>4)&3, jl = ng&15;
      int row = g*256 + w*64 + p*16 + jl;
      const float* s = (dir ? Whh_b : Whh_f) + (size_t)row*256 + 2*kp;
      wWs[id] = pack2(s[0], s[1]);
    } else if ((id -= N4) < N5) {        // sentence Wih packed [dir][kp][j][g], 306 = 153 pairs
      int dir = id >= 156672; int r = id - dir*156672;
      int g = r & 3, j = (r>>2)&255, kp = r>>10;
      const float* s = (dir ? Wih_b : Wih_f) + (size_t)(g*256+j)*306 + 2*kp;
      wWihs[id] = pack2(s[0], s[1]);
    } else if ((id -= N5) < N6) {        // sentence bias sums [dir][j][g]
      int g = id & 3, j = (id>>2)&255, dir = id>>10;
      int row = g*256+j;
      wbss[id] = dir ? (bih_b[row]+bhh_b[row]) : (bih_f[row]+bhh_f[row]);
    } else if ((id -= N6) < N7) {        // Wo packed [kp][o]
      int o = id & 31, kp = id>>5;
      const float* s = Wo + (size_t)o*512 + 2*kp;
      wWo[id] = pack2(s[0], s[1]);
    } else { id -= N7;                   // bert = Xw[:,20:198,0] -> sent[:,128:306]
      int wg = id / 178, ii = id % 178;
      sent[(size_t)wg*SROW + 128 + ii] = X[(size_t)wg*9900 + (20+ii)*50];
    }
  }
}

// ---- word LSTM via MFMA: 128 blocks x 16 words, 8 waves, N=512 (wave: 16 j x 4 gates).
__global__ __launch_bounds__(512, 2) void k_word(
    const float* __restrict__ X, const float* __restrict__ h0w, const float* __restrict__ c0w,
    const uint32_t* __restrict__ wWsw, const uint32_t* __restrict__ wWxw,
    const float* __restrict__ wbsw, const uint32_t* __restrict__ wWlf,
    const float* __restrict__ bl, float* __restrict__ sent)
{
  __shared__ __align__(16) uint32_t lets[11520];      // [t20][m16][36] f16x2 (72 cols, 50 real)
  __shared__ __align__(16) uint16_t hbuf[2][2176];    // [m16][136]
  const int tid = threadIdx.x;
  const int wave = tid >> 6, lane = tid & 63;
  const int l15 = lane & 15, l4 = lane >> 4;
  const int wg0 = blockIdx.x * 16;

  uint4 Bh[4][4], Bx[4][2];
  #pragma unroll
  for (int g = 0; g < 4; ++g) {
    int ng = wave*64 + g*16 + l15;
    #pragma unroll
    for (int Kt = 0; Kt < 4; ++Kt) Bh[g][Kt] = *(const uint4*)(wWsw + ng*64 + Kt*16 + l4*4);
    #pragma unroll
    for (int Kt = 0; Kt < 2; ++Kt) Bx[g][Kt] = *(const uint4*)(wWxw + ng*32 + Kt*16 + l4*4);
  }
  for (int i = tid; i < 11520; i += 512) {
    int c = i % 36, mt = i / 36; int m = mt & 15, t = mt >> 4;
    lets[i] = (c < 25) ? pack2(X[(size_t)(wg0+m)*9900 + t*50 + 2*c],
                               X[(size_t)(wg0+m)*9900 + t*50 + 2*c + 1]) : 0u;
  }
  for (int i = tid; i < 2048; i += 512) {
    int m = i >> 7, k = i & 127;
    hbuf[0][m*136 + k] = f16b(h0w[(size_t)(wg0+m)*128 + k]);
  }
  const float4 bs = *(const float4*)(wbsw + (wave*16 + l15)*4);
  float cr[4];
  #pragma unroll
  for (int r = 0; r < 4; ++r) cr[r] = c0w[(size_t)(wg0 + l4*4 + r)*128 + wave*16 + l15];
  __syncthreads();

  uint16_t* hc = hbuf[0];
  uint16_t* hn = hbuf[1];
  const uint16_t* lp = (const uint16_t*)lets;
  #pragma unroll 1
  for (int t = 0; t < 20; ++t) {
    f32x4_t acc[4];
    acc[0] = (f32x4_t){bs.x,bs.x,bs.x,bs.x};
    acc[1] = (f32x4_t){bs.y,bs.y,bs.y,bs.y};
    acc[2] = (f32x4_t){bs.z,bs.z,bs.z,bs.z};
    acc[3] = (f32x4_t){bs.w,bs.w,bs.w,bs.w};
    #pragma unroll
    for (int Kt = 0; Kt < 2; ++Kt) {
      uint4 av = *(const uint4*)(lp + (t*16 + l15)*72 + Kt*32 + l4*8);
      half8_t a = __builtin_bit_cast(half8_t, av);
      #pragma unroll
      for (int g = 0; g < 4; ++g)
        acc[g] = __builtin_amdgcn_mfma_f32_16x16x32_f16(a, __builtin_bit_cast(half8_t, Bx[g][Kt]), acc[g], 0,0,0);
    }
    #pragma unroll
    for (int Kt = 0; Kt < 4; ++Kt) {
      uint4 av = *(const uint4*)(hc + l15*136 + Kt*32 + l4*8);
      half8_t a = __builtin_bit_cast(half8_t, av);
      #pragma unroll
      for (int g = 0; g < 4; ++g)
        acc[g] = __builtin_amdgcn_mfma_f32_16x16x32_f16(a, __builtin_bit_cast(half8_t, Bh[g][Kt]), acc[g], 0,0,0);
    }
    #pragma unroll
    for (int r = 0; r < 4; ++r) {
      float cc = sigm(acc[1][r])*cr[r] + sigm(acc[0][r])*tanhf_(acc[2][r]);
      cr[r] = cc;
      float hh = sigm(acc[3][r])*tanhf_(cc);
      hn[(l4*4+r)*136 + wave*16 + l15] = f16b(hh);
    }
    uint16_t* tp = hc; hc = hn; hn = tp;
    __syncthreads();
  }
  uint4 Bl[4];
  #pragma unroll
  for (int Kt = 0; Kt < 4; ++Kt) Bl[Kt] = *(const uint4*)(wWlf + (wave*16 + l15)*64 + Kt*16 + l4*4);
  f32x4_t a2 = (f32x4_t){0.f,0.f,0.f,0.f};
  #pragma unroll
  for (int Kt = 0; Kt < 4; ++Kt) {
    uint4 av = *(const uint4*)(hc + l15*136 + Kt*32 + l4*8);
    a2 = __builtin_amdgcn_mfma_f32_16x16x32_f16(__builtin_bit_cast(half8_t, av),
                                                __builtin_bit_cast(half8_t, Bl[Kt]), a2, 0,0,0);
  }
  const float blv = bl[wave*16 + l15];
  #pragma unroll
  for (int r = 0; r < 4; ++r)
    sent[(size_t)(wg0 + l4*4 + r)*SROW + wave*16 + l15] = a2[r] + blv;
}

// ---- sentence xg GEMM -> xgq layout for 4-wave srec:
// uint2 idx = ((((dir*64+tt)*2+half)*4+w)*4+p)*256 + l15*16 + l4*4 + r
__global__ __launch_bounds__(256) void k_sxg(
    const float* __restrict__ sent, const uint32_t* __restrict__ Wihs,
    const float* __restrict__ bss, uint2* __restrict__ xgq)
{
  __shared__ uint32_t x16[153*8];
  const int tid = threadIdx.x;
  const int dir = blockIdx.x >> 8, rg = blockIdx.x & 255;
  for (int i = tid; i < 153*8; i += 256) {
    int r = i & 7, kp = i >> 3;
    int ot = rg*8 + r; int b = ot >> 6, tt = ot & 63;
    int si = dir ? (63 - tt) : tt;
    const float* s = sent + (size_t)(b*64 + si)*SROW + 2*kp;
    x16[kp*8 + r] = pack2(s[0], s[1]);
  }
  __syncthreads();
  const int j = tid;
  float acc[8][4];
  {
    const float4 b4 = *(const float4*)(bss + (dir*256 + j)*4);
    #pragma unroll
    for (int r = 0; r < 8; ++r) { acc[r][0]=b4.x; acc[r][1]=b4.y; acc[r][2]=b4.z; acc[r][3]=b4.w; }
  }
  for (int kp = 0; kp < 153; ++kp) {
    uint4 wv = *(const uint4*)(Wihs + ((size_t)(dir*153 + kp)*256 + j)*4);
    uint4 xa = *(const uint4*)(x16 + kp*8);
    uint4 xb = *(const uint4*)(x16 + kp*8 + 4);
    uint32_t wa[4] = {wv.x,wv.y,wv.z,wv.w};
    uint32_t xs[8] = {xa.x,xa.y,xa.z,xa.w,xb.x,xb.y,xb.z,xb.w};
    #pragma unroll
    for (int r = 0; r < 8; ++r)
      #pragma unroll
      for (int g = 0; g < 4; ++g) acc[r][g] = fdot2(wa[g], xs[r], acc[r][g]);
  }
  const int w = j >> 6, p = (j >> 4) & 3, l15j = j & 15;
  #pragma unroll
  for (int r = 0; r < 8; ++r) {
    int ot = rg*8 + r; int b = ot >> 6, tt = ot & 63;
    int half = b >> 4, m = b & 15;
    int l4m = m >> 2, rm = m & 3;
    uint2 v; v.x = pack2(acc[r][0], acc[r][1]); v.y = pack2(acc[r][2], acc[r][3]);
    size_t idx = ((((size_t)(dir*64 + tt)*2 + half)*4 + w)*4 + p)*256 + l15j*16 + l4m*4 + rm;
    xgq[idx] = v;
  }
}

// ---- sentence recurrence: grid 4 = (dir, batch-half M=16). 4 waves x 512 regs.
// Wave owns N=256 (16 Nt): Breg[4][4][6]=384 VGPR+AGPR, Kt{6,7} in LDS.
// 4 gate-grouped passes (4 Nt each), alternating acc pairs, depth-1 xg prefetch.
// outfb layout (halves): ((s*2+half)*2+dir)*16+m)*256 + j  (j = w*64+p*16+l15)
__global__ __launch_bounds__(256, 1) void k_srec(
    const uint32_t* __restrict__ Ws, const float* __restrict__ h0f, const float* __restrict__ c0f,
    const float* __restrict__ h0b, const float* __restrict__ c0b,
    const uint2* __restrict__ xgq, uint16_t* __restrict__ outfb)
{
  extern __shared__ char smem[];               // [0,131072) B-frags, then h dbuf 2x[16][HSTR]
  uint16_t* h16a = (uint16_t*)(smem + 131072);
  uint16_t* h16b = h16a + 16*HSTR;
  const int tid = threadIdx.x;
  const int wave = tid >> 6, lane = tid & 63;
  const int dir = blockIdx.x >> 1, half = blockIdx.x & 1, m0 = half * 16;
  const int l15 = lane & 15, l4 = lane >> 4;

  uint4 Breg[4][4][6];
  #pragma unroll
  for (int g = 0; g < 4; ++g)
    #pragma unroll
    for (int p = 0; p < 4; ++p) {
      int ng = wave*256 + g*64 + p*16 + l15;
      #pragma unroll
      for (int Kt = 0; Kt < 8; ++Kt) {
        uint4 v = *(const uint4*)(Ws + (size_t)(dir*1024 + ng)*128 + Kt*16 + l4*4);
        if (Kt < 6) Breg[g][p][Kt] = v;
        else *(uint4*)(smem + (((wave*32 + (g*4+p)*2 + (Kt-6))*64 + lane)*16)) = v;
      }
    }
  {
    const float* h0 = dir ? h0b : h0f;
    for (int i = tid; i < 16*256; i += 256) {
      int m = i >> 8, k = i & 255;
      h16a[m*HSTR + k] = f16b(h0[(size_t)(m0+m)*256 + k]);
    }
  }
  f32x4_t cr0, cr1, cr2, cr3;
  {
    const float* c0 = dir ? c0b : c0f;
    #pragma unroll
    for (int r = 0; r < 4; ++r) {
      cr0[r] = c0[(size_t)(m0 + l4*4 + r)*256 + wave*64 + 0*16 + l15];
      cr1[r] = c0[(size_t)(m0 + l4*4 + r)*256 + wave*64 + 1*16 + l15];
      cr2[r] = c0[(size_t)(m0 + l4*4 + r)*256 + wave*64 + 2*16 + l15];
      cr3[r] = c0[(size_t)(m0 + l4*4 + r)*256 + wave*64 + 3*16 + l15];
    }
  }
  __syncthreads();

  const char* xb = (const char*)xgq + (size_t)dir*4194304 + half*32768
                 + wave*8192 + l15*128 + l4*32;
  const int s0 = dir ? 63 : 0;
  const int sdelta = dir ? -32768 : 32768;
  char* op = (char*)outfb + (size_t)s0*32768 + half*16384 + dir*8192
           + (l4*4)*512 + wave*128 + l15*2;

  uint16_t* hc = h16a;
  uint16_t* hn = h16b;

#define XLOAD(P, XA, XB_) { XA = *(const uint4*)(xb + (P)*2048); XB_ = *(const uint4*)(xb + (P)*2048 + 16); }

#define PASS(P, XA, XB_, CRV) {                                                          \
    f32x4_t a0, a1, a2, a3;                                                              \
    a0 = (f32x4_t){lo16(XA.x), lo16(XA.z), lo16(XB_.x), lo16(XB_.z)};                    \
    a1 = (f32x4_t){hi16(XA.x), hi16(XA.z), hi16(XB_.x), hi16(XB_.z)};                    \
    a2 = (f32x4_t){lo16(XA.y), lo16(XA.w), lo16(XB_.y), lo16(XB_.w)};                    \
    a3 = (f32x4_t){hi16(XA.y), hi16(XA.w), hi16(XB_.y), hi16(XB_.w)};                    \
    _Pragma("unroll")                                                                    \
    for (int Kh = 0; Kh < 2; ++Kh) {                                                     \
      uint4 av0 = *(const uint4*)(hc + l15*HSTR + (Kh*4+0)*32 + l4*8);                   \
      uint4 av1 = *(const uint4*)(hc + l15*HSTR + (Kh*4+1)*32 + l4*8);                   \
      uint4 av2 = *(const uint4*)(hc + l15*HSTR + (Kh*4+2)*32 + l4*8);                   \
      uint4 av3 = *(const uint4*)(hc + l15*HSTR + (Kh*4+3)*32 + l4*8);                   \
      _Pragma("unroll")                                                                  \
      for (int g = 0; g < 4; ++g) {                                                      \
        f32x4_t* ac = (g==0)?&a0:(g==1)?&a1:(g==2)?&a2:&a3;                              \
        _Pragma("unroll")                                                                \
        for (int Kq = 0; Kq < 4; ++Kq) {                                                 \
          const int Kt = Kh*4 + Kq;                                                      \
          uint4 av = (Kq==0)?av0:(Kq==1)?av1:(Kq==2)?av2:av3;                            \
          uint4 bv;                                                                      \
          if (Kt < 6) bv = Breg[g][P][Kt];                                               \
          else bv = *(const uint4*)(smem + (((wave*32 + (g*4+(P))*2 + (Kt-6))*64 + lane)*16)); \
          *ac = __builtin_amdgcn_mfma_f32_16x16x32_f16(__builtin_bit_cast(half8_t, av),  \
                 __builtin_bit_cast(half8_t, bv), *ac, 0,0,0);                           \
        }                                                                                \
      }                                                                                  \
    }                                                                                    \
    _Pragma("unroll")                                                                    \
    for (int r = 0; r < 4; ++r) {                                                        \
      float gi = a0[r], gf = a1[r], gg = a2[r], go = a3[r];                              \
      float ef = __expf(-gf), ei = __expf(-gi), eg = __expf(-2.f*gg);                    \
      float pef = 1.f + ef, pei = 1.f + ei, peg = 1.f + eg;                              \
      float num = CRV[r]*pei*peg + (1.f - eg)*pef;                                       \
      float cc  = num * __builtin_amdgcn_rcpf(pef*pei*peg);                              \
      CRV[r] = cc;                                                                       \
      float ec = __expf(-2.f*cc), eo = __expf(-go);                                      \
      float hh = (1.f - ec) * __builtin_amdgcn_rcpf((1.f + ec)*(1.f + eo));              \
      uint16_t hb = f16b(hh);                                                            \
      hn[(l4*4+r)*HSTR + wave*64 + (P)*16 + l15] = hb;                                   \
      *(uint16_t*)(op + (P)*32 + r*512) = hb;                                            \
    }                                                                                    \
  }

  uint4 xpa, xpb, xqa, xqb;
  #pragma unroll 1
  for (int t = 0; t < 64; ++t) {
    XLOAD(0, xpa, xpb);
    XLOAD(1, xqa, xqb);
    PASS(0, xpa, xpb, cr0);
    XLOAD(2, xpa, xpb);
    PASS(1, xqa, xqb, cr1);
    XLOAD(3, xqa, xqb);
    PASS(2, xpa, xpb, cr2);
    PASS(3, xqa, xqb, cr3);

    { uint16_t* tp = hc; hc = hn; hn = tp; }
    xb += 65536;
    op += sdelta;
    asm volatile("s_waitcnt lgkmcnt(0)\ns_barrier" ::: "memory");
  }
#undef PASS
#undef XLOAD
}

// ---- tags + softmax (reads the srec outfb layout: [s][half][dir][m][j])
__global__ __launch_bounds__(256) void k_tags(
    const uint16_t* __restrict__ outfb, const uint32_t* __restrict__ Wo16,
    const float* __restrict__ bo, float* __restrict__ out)
{
  __shared__ uint32_t xr[8*256];
  const int tid = threadIdx.x;
  const int w0 = blockIdx.x * 8;
  const uint32_t* src = (const uint32_t*)outfb;
  for (int i = tid; i < 2048; i += 256) {
    int w = i >> 8, kp = i & 255;                // kp: u32 over k = dir*256 + j, pairs jp=j>>1
    int widx = w0 + w;
    int s = widx & 63, q = widx >> 6;
    int half = q >> 4, m = q & 15;
    int dir = kp >> 7, jp = kp & 127;
    xr[i] = src[s*8192 + half*4096 + dir*2048 + m*128 + jp];
  }
  __syncthreads();
  const int o = tid & 31, w = tid >> 5;
  float a = bo[o];
  for (int kp = 0; kp < 256; ++kp)
    a = fdot2(Wo16[kp*32 + o], xr[w*256 + kp], a);
  float mx = a;
  #pragma unroll
  for (int off = 16; off; off >>= 1) mx = fmaxf(mx, __shfl_xor(mx, off, 32));
  float e = __expf(a - mx);
  float ssum = e;
  #pragma unroll
  for (int off = 16; off; off >>= 1) ssum += __shfl_xor(ssum, off, 32);
  out[(size_t)(w0+w)*32 + o] = e * __builtin_amdgcn_rcpf(ssum);
}

extern "C" void kernel_launch(void* const* d_in, const int* in_sizes, int n_in,
                              void* d_out, int out_size, void* d_ws, size_t ws_size,
                              hipStream_t stream) {
  const float* X     = (const float*)d_in[0];
  const float* h0w   = (const float*)d_in[1];
  const float* c0w   = (const float*)d_in[2];
  const float* h0f   = (const float*)d_in[3];
  const float* c0f   = (const float*)d_in[4];
  const float* h0b   = (const float*)d_in[5];
  const float* c0b   = (const float*)d_in[6];
  const float* Wih_w = (const float*)d_in[7];
  const float* Whh_w = (const float*)d_in[8];
  const float* bih_w = (const float*)d_in[9];
  const float* bhh_w = (const float*)d_in[10];
  const float* Wl    = (const float*)d_in[11];
  const float* bl    = (const float*)d_in[12];
  const float* Wih_f = (const float*)d_in[13];
  const float* Whh_f = (const float*)d_in[14];
  const float* bih_f = (const float*)d_in[15];
  const float* bhh_f = (const float*)d_in[16];
  const float* Wih_b = (const float*)d_in[17];
  const float* Whh_b = (const float*)d_in[18];
  const float* bih_b = (const float*)d_in[19];
  const float* bhh_b = (const float*)d_in[20];
  const float* Wo    = (const float*)d_in[21];
  const float* bo    = (const float*)d_in[22];

  char* ws = (char*)d_ws;
  uint32_t* wWsw  = (uint32_t*)(ws + 0);          // 131072 B
  uint32_t* wWxw  = (uint32_t*)(ws + 131072);     // 65536 B
  uint32_t* wWlf  = (uint32_t*)(ws + 196608);     // 32768 B
  float*    wbsw  = (float*)   (ws + 229376);     // 2048 B
  uint32_t* wWs   = (uint32_t*)(ws + 231424);     // 1048576 B
  uint32_t* wWihs = (uint32_t*)(ws + 1280000);    // 1253376 B
  float*    wbss  = (float*)   (ws + 2533376);    // 8192 B
  uint32_t* wWo   = (uint32_t*)(ws + 2541568);    // 32768 B
  float*    sent  = (float*)   (ws + 2574336);    // 2523136 B
  uint2*    xgq   = (uint2*)   (ws + 5097472);    // 8388608 B
  uint16_t* outfb = (uint16_t*)(ws + 13486080);   // 2097152 B -> end ~15.6 MB

  hipFuncSetAttribute((const void*)k_srec, hipFuncAttributeMaxDynamicSharedMemorySize, 148992);

  k_prep<<<2048, 256, 0, stream>>>(X, Wih_w, Whh_w, bih_w, bhh_w, Wl, Wih_f, Whh_f, bih_f, bhh_f,
                                   Wih_b, Whh_b, bih_b, bhh_b, Wo,
                                   wWsw, wWxw, wWlf, wbsw, wWs, wWihs, wbss, wWo, sent);
  k_word<<<128, 512, 0, stream>>>(X, h0w, c0w, wWsw, wWxw, wbsw, wWlf, bl, sent);
  k_sxg<<<512, 256, 0, stream>>>(sent, wWihs, wbss, xgq);
  k_srec<<<4, 256, 148992, stream>>>(wWs, h0f, c0f, h0b, c0b, xgq, outfb);
  k_tags<<<256, 256, 0, stream>>>(outfb, wWo, bo, (float*)d_out);
}

// Round 6
// 349.452 us; speedup vs baseline: 1.3250x; 1.3250x over previous
//
#include <hip/hip_runtime.h>
#include <cstdint>
#include <cstddef>

#define DI static __device__ __forceinline__

using half_t  = _Float16;
using half2_t = __attribute__((ext_vector_type(2))) _Float16;
using half8_t = __attribute__((ext_vector_type(8))) _Float16;
using f32x4_t = __attribute__((ext_vector_type(4))) float;

DI uint32_t pack2(float a, float b){ half2_t h; h[0]=(half_t)a; h[1]=(half_t)b; return __builtin_bit_cast(uint32_t,h); }
DI uint16_t f16b(float a){ return __builtin_bit_cast(uint16_t,(half_t)a); }
DI float lo16(uint32_t u){ half2_t h=__builtin_bit_cast(half2_t,u); return (float)h[0]; }
DI float hi16(uint32_t u){ half2_t h=__builtin_bit_cast(half2_t,u); return (float)h[1]; }
DI float fdot2(uint32_t w, uint32_t x, float acc){
  return __builtin_amdgcn_fdot2(__builtin_bit_cast(half2_t,w), __builtin_bit_cast(half2_t,x), acc, false);
}
DI float sigm(float x){ return __builtin_amdgcn_rcpf(1.f + __expf(-x)); }
DI float tanhf_(float x){ return 1.f - 2.f*__builtin_amdgcn_rcpf(__expf(2.f*x)+1.f); }

// problem sizes: B=32 S=64 NW=2048 T=198 L=50 WLEN=20 BERT=178 Hs=128 Hm=256 Din=306 O=32
#define SROW 308   // sentences_in row stride (306 used)
#define HSTR 280   // k_srec h-row stride in halves (560 B rows)

// prep job sizes
#define N0 32768   // word Whh MFMA-B frags [ng512][kp64]
#define N1 16384   // word Wih MFMA-B frags [ng512][kp32] (k=50 zero-padded to 64)
#define N2 8192    // Wl B-frags [d128][kp64]
#define N3 512     // word bias sum [j128][g4]
#define N4 262144  // sent Whh B-frag layout [dir][ng1024][kp128], ng = w*64 + g*16 + jl
#define N5 313344  // sent Wih f16x2 [dir][kp153][j256][g4]
#define N6 2048    // sent bias sum [dir][j256][g4]
#define N7 8192    // Wo f16x2 [kp256][o32]
#define N8 364544  // bert -> sent[:,128:306]
#define NTOT (N0+N1+N2+N3+N4+N5+N6+N7+N8)

__global__ void k_prep(const float* __restrict__ X,
                       const float* __restrict__ Wih_w, const float* __restrict__ Whh_w,
                       const float* __restrict__ bih_w, const float* __restrict__ bhh_w,
                       const float* __restrict__ Wl,
                       const float* __restrict__ Wih_f, const float* __restrict__ Whh_f,
                       const float* __restrict__ bih_f, const float* __restrict__ bhh_f,
                       const float* __restrict__ Wih_b, const float* __restrict__ Whh_b,
                       const float* __restrict__ bih_b, const float* __restrict__ bhh_b,
                       const float* __restrict__ Wo,
                       uint32_t* __restrict__ wWsw, uint32_t* __restrict__ wWxw,
                       uint32_t* __restrict__ wWlf, float* __restrict__ wbsw,
                       uint32_t* __restrict__ wWs, uint32_t* __restrict__ wWihs,
                       float* __restrict__ wbss, uint32_t* __restrict__ wWo,
                       float* __restrict__ sent)
{
  for (int i = blockIdx.x*blockDim.x + threadIdx.x; i < NTOT; i += gridDim.x*blockDim.x) {
    int id = i;
    if (id < N0) {                       // word Whh B-frags: ng = w*64+g*16+jl -> row g*128+w*16+jl
      int kp = id & 63, ng = id >> 6;
      int w = ng>>6, g = (ng>>4)&3, jl = ng&15;
      const float* s = Whh_w + (size_t)(g*128 + w*16 + jl)*128 + 2*kp;
      wWsw[id] = pack2(s[0], s[1]);
    } else if ((id -= N0) < N1) {        // word Wih B-frags, k padded 50->64
      int kp = id & 31, ng = id >> 5;
      int w = ng>>6, g = (ng>>4)&3, jl = ng&15;
      if (kp < 25) {
        const float* s = Wih_w + (size_t)(g*128 + w*16 + jl)*50 + 2*kp;
        wWxw[id] = pack2(s[0], s[1]);
      } else wWxw[id] = 0u;
    } else if ((id -= N1) < N2) {        // Wl B-frags [d][kp]
      int kp = id & 63, d = id >> 6;
      const float* s = Wl + (size_t)d*128 + 2*kp;
      wWlf[id] = pack2(s[0], s[1]);
    } else if ((id -= N2) < N3) {        // word bias sum [j][g]
      int g = id & 3, j = id>>2;
      wbsw[id] = bih_w[g*128+j] + bhh_w[g*128+j];
    } else if ((id -= N3) < N4) {        // sentence Whh: ng = w*64 + g*16 + jl -> row g*256 + w*16 + jl
      int kp = id & 127, ng = (id>>7)&1023, dir = id>>17;
      int w = ng>>6, g = (ng>>4)&3, jl = ng&15;
      int row = g*256 + w*16 + jl;
      const float* s = (dir ? Whh_b : Whh_f) + (size_t)row*256 + 2*kp;
      wWs[id] = pack2(s[0], s[1]);
    } else if ((id -= N4) < N5) {        // sentence Wih packed [dir][kp][j][g], 306 = 153 pairs
      int dir = id >= 156672; int r = id - dir*156672;
      int g = r & 3, j = (r>>2)&255, kp = r>>10;
      const float* s = (dir ? Wih_b : Wih_f) + (size_t)(g*256+j)*306 + 2*kp;
      wWihs[id] = pack2(s[0], s[1]);
    } else if ((id -= N5) < N6) {        // sentence bias sums [dir][j][g]
      int g = id & 3, j = (id>>2)&255, dir = id>>10;
      int row = g*256+j;
      wbss[id] = dir ? (bih_b[row]+bhh_b[row]) : (bih_f[row]+bhh_f[row]);
    } else if ((id -= N6) < N7) {        // Wo packed [kp][o]
      int o = id & 31, kp = id>>5;
      const float* s = Wo + (size_t)o*512 + 2*kp;
      wWo[id] = pack2(s[0], s[1]);
    } else { id -= N7;                   // bert = Xw[:,20:198,0] -> sent[:,128:306]
      int wg = id / 178, ii = id % 178;
      sent[(size_t)wg*SROW + 128 + ii] = X[(size_t)wg*9900 + (20+ii)*50];
    }
  }
}

// ---- word LSTM via MFMA: 128 blocks x 16 words, 8 waves, N=512 (wave: 16 j x 4 gates).
__global__ __launch_bounds__(512, 2) void k_word(
    const float* __restrict__ X, const float* __restrict__ h0w, const float* __restrict__ c0w,
    const uint32_t* __restrict__ wWsw, const uint32_t* __restrict__ wWxw,
    const float* __restrict__ wbsw, const uint32_t* __restrict__ wWlf,
    const float* __restrict__ bl, float* __restrict__ sent)
{
  __shared__ __align__(16) uint32_t lets[11520];      // [t20][m16][36] f16x2 (72 cols, 50 real)
  __shared__ __align__(16) uint16_t hbuf[2][2176];    // [m16][136]
  const int tid = threadIdx.x;
  const int wave = tid >> 6, lane = tid & 63;
  const int l15 = lane & 15, l4 = lane >> 4;
  const int wg0 = blockIdx.x * 16;

  uint4 Bh[4][4], Bx[4][2];
  #pragma unroll
  for (int g = 0; g < 4; ++g) {
    int ng = wave*64 + g*16 + l15;
    #pragma unroll
    for (int Kt = 0; Kt < 4; ++Kt) Bh[g][Kt] = *(const uint4*)(wWsw + ng*64 + Kt*16 + l4*4);
    #pragma unroll
    for (int Kt = 0; Kt < 2; ++Kt) Bx[g][Kt] = *(const uint4*)(wWxw + ng*32 + Kt*16 + l4*4);
  }
  for (int i = tid; i < 11520; i += 512) {
    int c = i % 36, mt = i / 36; int m = mt & 15, t = mt >> 4;
    lets[i] = (c < 25) ? pack2(X[(size_t)(wg0+m)*9900 + t*50 + 2*c],
                               X[(size_t)(wg0+m)*9900 + t*50 + 2*c + 1]) : 0u;
  }
  for (int i = tid; i < 2048; i += 512) {
    int m = i >> 7, k = i & 127;
    hbuf[0][m*136 + k] = f16b(h0w[(size_t)(wg0+m)*128 + k]);
  }
  const float4 bs = *(const float4*)(wbsw + (wave*16 + l15)*4);
  float cr[4];
  #pragma unroll
  for (int r = 0; r < 4; ++r) cr[r] = c0w[(size_t)(wg0 + l4*4 + r)*128 + wave*16 + l15];
  __syncthreads();

  uint16_t* hc = hbuf[0];
  uint16_t* hn = hbuf[1];
  const uint16_t* lp = (const uint16_t*)lets;
  #pragma unroll 1
  for (int t = 0; t < 20; ++t) {
    f32x4_t acc[4];
    acc[0] = (f32x4_t){bs.x,bs.x,bs.x,bs.x};
    acc[1] = (f32x4_t){bs.y,bs.y,bs.y,bs.y};
    acc[2] = (f32x4_t){bs.z,bs.z,bs.z,bs.z};
    acc[3] = (f32x4_t){bs.w,bs.w,bs.w,bs.w};
    #pragma unroll
    for (int Kt = 0; Kt < 2; ++Kt) {
      uint4 av = *(const uint4*)(lp + (t*16 + l15)*72 + Kt*32 + l4*8);
      half8_t a = __builtin_bit_cast(half8_t, av);
      #pragma unroll
      for (int g = 0; g < 4; ++g)
        acc[g] = __builtin_amdgcn_mfma_f32_16x16x32_f16(a, __builtin_bit_cast(half8_t, Bx[g][Kt]), acc[g], 0,0,0);
    }
    #pragma unroll
    for (int Kt = 0; Kt < 4; ++Kt) {
      uint4 av = *(const uint4*)(hc + l15*136 + Kt*32 + l4*8);
      half8_t a = __builtin_bit_cast(half8_t, av);
      #pragma unroll
      for (int g = 0; g < 4; ++g)
        acc[g] = __builtin_amdgcn_mfma_f32_16x16x32_f16(a, __builtin_bit_cast(half8_t, Bh[g][Kt]), acc[g], 0,0,0);
    }
    #pragma unroll
    for (int r = 0; r < 4; ++r) {
      float cc = sigm(acc[1][r])*cr[r] + sigm(acc[0][r])*tanhf_(acc[2][r]);
      cr[r] = cc;
      float hh = sigm(acc[3][r])*tanhf_(cc);
      hn[(l4*4+r)*136 + wave*16 + l15] = f16b(hh);
    }
    uint16_t* tp = hc; hc = hn; hn = tp;
    __syncthreads();
  }
  uint4 Bl[4];
  #pragma unroll
  for (int Kt = 0; Kt < 4; ++Kt) Bl[Kt] = *(const uint4*)(wWlf + (wave*16 + l15)*64 + Kt*16 + l4*4);
  f32x4_t a2 = (f32x4_t){0.f,0.f,0.f,0.f};
  #pragma unroll
  for (int Kt = 0; Kt < 4; ++Kt) {
    uint4 av = *(const uint4*)(hc + l15*136 + Kt*32 + l4*8);
    a2 = __builtin_amdgcn_mfma_f32_16x16x32_f16(__builtin_bit_cast(half8_t, av),
                                                __builtin_bit_cast(half8_t, Bl[Kt]), a2, 0,0,0);
  }
  const float blv = bl[wave*16 + l15];
  #pragma unroll
  for (int r = 0; r < 4; ++r)
    sent[(size_t)(wg0 + l4*4 + r)*SROW + wave*16 + l15] = a2[r] + blv;
}

// ---- sentence xg GEMM -> xgq for 16-wave srec:
// uint2 idx = (((dir*64+tt)*2+half)*16 + w)*256 + l15*16 + l4*4 + r   (w = j>>4)
__global__ __launch_bounds__(256) void k_sxg(
    const float* __restrict__ sent, const uint32_t* __restrict__ Wihs,
    const float* __restrict__ bss, uint2* __restrict__ xgq)
{
  __shared__ uint32_t x16[153*8];
  const int tid = threadIdx.x;
  const int dir = blockIdx.x >> 8, rg = blockIdx.x & 255;
  for (int i = tid; i < 153*8; i += 256) {
    int r = i & 7, kp = i >> 3;
    int ot = rg*8 + r; int b = ot >> 6, tt = ot & 63;
    int si = dir ? (63 - tt) : tt;
    const float* s = sent + (size_t)(b*64 + si)*SROW + 2*kp;
    x16[kp*8 + r] = pack2(s[0], s[1]);
  }
  __syncthreads();
  const int j = tid;
  float acc[8][4];
  {
    const float4 b4 = *(const float4*)(bss + (dir*256 + j)*4);
    #pragma unroll
    for (int r = 0; r < 8; ++r) { acc[r][0]=b4.x; acc[r][1]=b4.y; acc[r][2]=b4.z; acc[r][3]=b4.w; }
  }
  for (int kp = 0; kp < 153; ++kp) {
    uint4 wv = *(const uint4*)(Wihs + ((size_t)(dir*153 + kp)*256 + j)*4);
    uint4 xa = *(const uint4*)(x16 + kp*8);
    uint4 xb = *(const uint4*)(x16 + kp*8 + 4);
    uint32_t wa[4] = {wv.x,wv.y,wv.z,wv.w};
    uint32_t xs[8] = {xa.x,xa.y,xa.z,xa.w,xb.x,xb.y,xb.z,xb.w};
    #pragma unroll
    for (int r = 0; r < 8; ++r)
      #pragma unroll
      for (int g = 0; g < 4; ++g) acc[r][g] = fdot2(wa[g], xs[r], acc[r][g]);
  }
  const int w = j >> 4, l15j = j & 15;
  #pragma unroll
  for (int r = 0; r < 8; ++r) {
    int ot = rg*8 + r; int b = ot >> 6, tt = ot & 63;
    int half = b >> 4, m = b & 15;
    int l4m = m >> 2, rm = m & 3;
    uint2 v; v.x = pack2(acc[r][0], acc[r][1]); v.y = pack2(acc[r][2], acc[r][3]);
    size_t idx = (((size_t)(dir*64 + tt)*2 + half)*16 + w)*256 + l15j*16 + l4m*4 + rm;
    xgq[idx] = v;
  }
}

// ---- sentence recurrence: grid 4 = (dir, batch-half M=16). 16 waves (4/SIMD, 128 VGPR cap).
// Wave owns N=64 = 16 j x 4 gates: Breg[4][6] = 96 regs, Kt{6,7} in LDS (128 KB).
// Per step/wave: 8 A ds_reads + 8 B-LDS reads + 32 MFMA + 4-output update.
// outfb layout (halves): ((s*2+half)*2+dir)*4096 + m*256 + j   (j = w*16 + l15)
__global__ __launch_bounds__(1024, 1) void k_srec(
    const uint32_t* __restrict__ Ws, const float* __restrict__ h0f, const float* __restrict__ c0f,
    const float* __restrict__ h0b, const float* __restrict__ c0b,
    const uint2* __restrict__ xgq, uint16_t* __restrict__ outfb)
{
  extern __shared__ char smem[];               // [0,131072) B-frags, then h dbuf 2x[16][HSTR]
  const int tid = threadIdx.x;
  const int wave = tid >> 6, lane = tid & 63;
  const int dir = blockIdx.x >> 1, half = blockIdx.x & 1, m0 = half * 16;
  const int l15 = lane & 15, l4 = lane >> 4;

  uint4 Breg[4][6];
  #pragma unroll
  for (int g = 0; g < 4; ++g) {
    int ng = wave*64 + g*16 + l15;
    #pragma unroll
    for (int Kt = 0; Kt < 8; ++Kt) {
      uint4 v = *(const uint4*)(Ws + (size_t)(dir*1024 + ng)*128 + Kt*16 + l4*4);
      if (Kt < 6) Breg[g][Kt] = v;
      else *(uint4*)(smem + (((wave*8 + g*2 + (Kt-6))*64 + lane)*16)) = v;
    }
  }
  {
    uint16_t* h16a = (uint16_t*)(smem + 131072);
    const float* h0 = dir ? h0b : h0f;
    for (int i = tid; i < 16*256; i += 1024) {
      int m = i >> 8, k = i & 255;
      h16a[m*HSTR + k] = f16b(h0[(size_t)(m0+m)*256 + k]);
    }
  }
  float cr[4];
  {
    const float* c0 = dir ? c0b : c0f;
    #pragma unroll
    for (int r = 0; r < 4; ++r)
      cr[r] = c0[(size_t)(m0 + l4*4 + r)*256 + wave*16 + l15];
  }
  __syncthreads();

  // uniform bases stay scalar; per-lane offsets are single VGPRs
  const uint32_t xlane = wave*2048 + l15*128 + l4*32;
  const char* xbase = (const char*)xgq + (size_t)dir*4194304 + half*32768;
  const uint32_t olane = (l4*4)*512 + wave*32 + l15*2;
  char* obase = (char*)outfb + half*16384 + dir*8192;
  const uint32_t aoff = l15*HSTR + l4*8;       // A-frag half-offset within h row-block

  #pragma unroll 1
  for (int t = 0; t < 64; ++t) {
    const char* xp = xbase + (size_t)t*65536 + xlane;
    uint4 xa  = *(const uint4*)(xp);
    uint4 xb2 = *(const uint4*)(xp + 16);
    f32x4_t a0 = (f32x4_t){lo16(xa.x), lo16(xa.z), lo16(xb2.x), lo16(xb2.z)};  // i
    f32x4_t a1 = (f32x4_t){hi16(xa.x), hi16(xa.z), hi16(xb2.x), hi16(xb2.z)};  // f
    f32x4_t a2 = (f32x4_t){lo16(xa.y), lo16(xa.w), lo16(xb2.y), lo16(xb2.w)};  // g
    f32x4_t a3 = (f32x4_t){hi16(xa.y), hi16(xa.w), hi16(xb2.y), hi16(xb2.w)};  // o

    const uint16_t* hc = (const uint16_t*)(smem + 131072 + (t & 1)*8960);
    uint16_t* hn = (uint16_t*)(smem + 131072 + ((t & 1) ^ 1)*8960);

    #pragma unroll
    for (int Kt = 0; Kt < 8; ++Kt) {
      uint4 av = *(const uint4*)(hc + aoff + Kt*32);
      half8_t a = __builtin_bit_cast(half8_t, av);
      #pragma unroll
      for (int g = 0; g < 4; ++g) {
        uint4 bv;
        if (Kt < 6) bv = Breg[g][Kt];
        else bv = *(const uint4*)(smem + (((wave*8 + g*2 + (Kt-6))*64 + lane)*16));
        f32x4_t* ac = (g==0)?&a0:(g==1)?&a1:(g==2)?&a2:&a3;
        *ac = __builtin_amdgcn_mfma_f32_16x16x32_f16(a, __builtin_bit_cast(half8_t, bv), *ac, 0,0,0);
      }
    }

    const int s = dir ? (63 - t) : t;
    char* op = obase + (size_t)s*32768 + olane;
    #pragma unroll
    for (int r = 0; r < 4; ++r) {
      float gi = a0[r], gf = a1[r], gg = a2[r], go = a3[r];
      // fused-denominator LSTM update: 5 exp + 2 rcp
      float ef = __expf(-gf), ei = __expf(-gi), eg = __expf(-2.f*gg);
      float pef = 1.f + ef, pei = 1.f + ei, peg = 1.f + eg;
      float num = cr[r]*pei*peg + (1.f - eg)*pef;
      float cc  = num * __builtin_amdgcn_rcpf(pef*pei*peg);
      cr[r] = cc;
      float ec = __expf(-2.f*cc), eo = __expf(-go);
      float hh = (1.f - ec) * __builtin_amdgcn_rcpf((1.f + ec)*(1.f + eo));
      uint16_t hb = f16b(hh);
      hn[(l4*4+r)*HSTR + wave*16 + l15] = hb;
      *(uint16_t*)(op + r*512) = hb;
    }
    // h dbuf: drain this step's LDS writes only; global traffic flies across
    asm volatile("s_waitcnt lgkmcnt(0)\ns_barrier" ::: "memory");
  }
}

// ---- tags + softmax (reads srec outfb layout: [s][half][dir][m][j])
__global__ __launch_bounds__(256) void k_tags(
    const uint16_t* __restrict__ outfb, const uint32_t* __restrict__ Wo16,
    const float* __restrict__ bo, float* __restrict__ out)
{
  __shared__ uint32_t xr[8*256];
  const int tid = threadIdx.x;
  const int w0 = blockIdx.x * 8;
  const uint32_t* src = (const uint32_t*)outfb;
  for (int i = tid; i < 2048; i += 256) {
    int w = i >> 8, kp = i & 255;                // kp: u32 over k = dir*256 + j, pairs jp = j>>1
    int widx = w0 + w;
    int s = widx & 63, q = widx >> 6;
    int half = q >> 4, m = q & 15;
    int dir = kp >> 7, jp = kp & 127;
    xr[i] = src[s*8192 + half*4096 + dir*2048 + m*128 + jp];
  }
  __syncthreads();
  const int o = tid & 31, w = tid >> 5;
  float a = bo[o];
  for (int kp = 0; kp < 256; ++kp)
    a = fdot2(Wo16[kp*32 + o], xr[w*256 + kp], a);
  float mx = a;
  #pragma unroll
  for (int off = 16; off; off >>= 1) mx = fmaxf(mx, __shfl_xor(mx, off, 32));
  float e = __expf(a - mx);
  float ssum = e;
  #pragma unroll
  for (int off = 16; off; off >>= 1) ssum += __shfl_xor(ssum, off, 32);
  out[(size_t)(w0+w)*32 + o] = e * __builtin_amdgcn_rcpf(ssum);
}

extern "C" void kernel_launch(void* const* d_in, const int* in_sizes, int n_in,
                              void* d_out, int out_size, void* d_ws, size_t ws_size,
                              hipStream_t stream) {
  const float* X     = (const float*)d_in[0];
  const float* h0w   = (const float*)d_in[1];
  const float* c0w   = (const float*)d_in[2];
  const float* h0f   = (const float*)d_in[3];
  const float* c0f   = (const float*)d_in[4];
  const float* h0b   = (const float*)d_in[5];
  const float* c0b   = (const float*)d_in[6];
  const float* Wih_w = (const float*)d_in[7];
  const float* Whh_w = (const float*)d_in[8];
  const float* bih_w = (const float*)d_in[9];
  const float* bhh_w = (const float*)d_in[10];
  const float* Wl    = (const float*)d_in[11];
  const float* bl    = (const float*)d_in[12];
  const float* Wih_f = (const float*)d_in[13];
  const float* Whh_f = (const float*)d_in[14];
  const float* bih_f = (const float*)d_in[15];
  const float* bhh_f = (const float*)d_in[16];
  const float* Wih_b = (const float*)d_in[17];
  const float* Whh_b = (const float*)d_in[18];
  const float* bih_b = (const float*)d_in[19];
  const float* bhh_b = (const float*)d_in[20];
  const float* Wo    = (const float*)d_in[21];
  const float* bo    = (const float*)d_in[22];

  char* ws = (char*)d_ws;
  uint32_t* wWsw  = (uint32_t*)(ws + 0);          // 131072 B
  uint32_t* wWxw  = (uint32_t*)(ws + 131072);     // 65536 B
  uint32_t* wWlf  = (uint32_t*)(ws + 196608);     // 32768 B
  float*    wbsw  = (float*)   (ws + 229376);     // 2048 B
  uint32_t* wWs   = (uint32_t*)(ws + 231424);     // 1048576 B
  uint32_t* wWihs = (uint32_t*)(ws + 1280000);    // 1253376 B
  float*    wbss  = (float*)   (ws + 2533376);    // 8192 B
  uint32_t* wWo   = (uint32_t*)(ws + 2541568);    // 32768 B
  float*    sent  = (float*)   (ws + 2574336);    // 2523136 B
  uint2*    xgq   = (uint2*)   (ws + 5097472);    // 8388608 B
  uint16_t* outfb = (uint16_t*)(ws + 13486080);   // 2097152 B -> end ~15.6 MB

  hipFuncSetAttribute((const void*)k_srec, hipFuncAttributeMaxDynamicSharedMemorySize, 148992);

  k_prep<<<2048, 256, 0, stream>>>(X, Wih_w, Whh_w, bih_w, bhh_w, Wl, Wih_f, Whh_f, bih_f, bhh_f,
                                   Wih_b, Whh_b, bih_b, bhh_b, Wo,
                                   wWsw, wWxw, wWlf, wbsw, wWs, wWihs, wbss, wWo, sent);
  k_word<<<128, 512, 0, stream>>>(X, h0w, c0w, wWsw, wWxw, wbsw, wWlf, bl, sent);
  k_sxg<<<512, 256, 0, stream>>>(sent, wWihs, wbss, xgq);
  k_srec<<<4, 1024, 148992, stream>>>(wWs, h0f, c0f, h0b, c0b, xgq, outfb);
  k_tags<<<256, 256, 0, stream>>>(outfb, wWo, bo, (float*)d_out);
}

// Round 7
// 310.745 us; speedup vs baseline: 1.4901x; 1.1246x over previous
//
#include <hip/hip_runtime.h>
#include <cstdint>
#include <cstddef>

#define DI static __device__ __forceinline__

using half_t  = _Float16;
using half2_t = __attribute__((ext_vector_type(2))) _Float16;
using half8_t = __attribute__((ext_vector_type(8))) _Float16;
using f32x4_t = __attribute__((ext_vector_type(4))) float;

DI uint32_t pack2(float a, float b){ half2_t h; h[0]=(half_t)a; h[1]=(half_t)b; return __builtin_bit_cast(uint32_t,h); }
DI uint16_t f16b(float a){ return __builtin_bit_cast(uint16_t,(half_t)a); }
DI float lo16(uint32_t u){ half2_t h=__builtin_bit_cast(half2_t,u); return (float)h[0]; }
DI float hi16(uint32_t u){ half2_t h=__builtin_bit_cast(half2_t,u); return (float)h[1]; }
DI float fdot2(uint32_t w, uint32_t x, float acc){
  return __builtin_amdgcn_fdot2(__builtin_bit_cast(half2_t,w), __builtin_bit_cast(half2_t,x), acc, false);
}
DI float sigm(float x){ return __builtin_amdgcn_rcpf(1.f + __expf(-x)); }
DI float tanhf_(float x){ return 1.f - 2.f*__builtin_amdgcn_rcpf(__expf(2.f*x)+1.f); }

// problem sizes: B=32 S=64 NW=2048 T=198 L=50 WLEN=20 BERT=178 Hs=128 Hm=256 Din=306 O=32
#define SROW 308   // sentences_in row stride (306 used)
#define HSTR 280   // k_srec h-row stride in halves (560 B = free 2-way banks)

// prep job sizes
#define N0 32768   // word Whh MFMA-B frags [ng512][kp64]
#define N1 16384   // word Wih MFMA-B frags [ng512][kp32] (k=50 zero-padded to 64)
#define N2 8192    // Wl B-frags [d128][kp64]
#define N3 512     // word bias sum [j128][g4]
#define N4 262144  // sent Whh B-frag layout [dir][ng1024][kp128], ng = w*128 + g*32 + jh*16 + jl
#define N5 313344  // sent Wih f16x2 [dir][kp153][j256][g4]
#define N6 2048    // sent bias sum [dir][j256][g4]
#define N7 8192    // Wo f16x2 [kp256][o32]
#define N8 364544  // bert -> sent[:,128:306]
#define NTOT (N0+N1+N2+N3+N4+N5+N6+N7+N8)

__global__ void k_prep(const float* __restrict__ X,
                       const float* __restrict__ Wih_w, const float* __restrict__ Whh_w,
                       const float* __restrict__ bih_w, const float* __restrict__ bhh_w,
                       const float* __restrict__ Wl,
                       const float* __restrict__ Wih_f, const float* __restrict__ Whh_f,
                       const float* __restrict__ bih_f, const float* __restrict__ bhh_f,
                       const float* __restrict__ Wih_b, const float* __restrict__ Whh_b,
                       const float* __restrict__ bih_b, const float* __restrict__ bhh_b,
                       const float* __restrict__ Wo,
                       uint32_t* __restrict__ wWsw, uint32_t* __restrict__ wWxw,
                       uint32_t* __restrict__ wWlf, float* __restrict__ wbsw,
                       uint32_t* __restrict__ wWs, uint32_t* __restrict__ wWihs,
                       float* __restrict__ wbss, uint32_t* __restrict__ wWo,
                       float* __restrict__ sent)
{
  for (int i = blockIdx.x*blockDim.x + threadIdx.x; i < NTOT; i += gridDim.x*blockDim.x) {
    int id = i;
    if (id < N0) {                       // word Whh B-frags: ng = w*64+g*16+jl -> row g*128+w*16+jl
      int kp = id & 63, ng = id >> 6;
      int w = ng>>6, g = (ng>>4)&3, jl = ng&15;
      const float* s = Whh_w + (size_t)(g*128 + w*16 + jl)*128 + 2*kp;
      wWsw[id] = pack2(s[0], s[1]);
    } else if ((id -= N0) < N1) {        // word Wih B-frags, k padded 50->64
      int kp = id & 31, ng = id >> 5;
      int w = ng>>6, g = (ng>>4)&3, jl = ng&15;
      if (kp < 25) {
        const float* s = Wih_w + (size_t)(g*128 + w*16 + jl)*50 + 2*kp;
        wWxw[id] = pack2(s[0], s[1]);
      } else wWxw[id] = 0u;
    } else if ((id -= N1) < N2) {        // Wl B-frags [d][kp]
      int kp = id & 63, d = id >> 6;
      const float* s = Wl + (size_t)d*128 + 2*kp;
      wWlf[id] = pack2(s[0], s[1]);
    } else if ((id -= N2) < N3) {        // word bias sum [j][g]
      int g = id & 3, j = id>>2;
      wbsw[id] = bih_w[g*128+j] + bhh_w[g*128+j];
    } else if ((id -= N3) < N4) {        // sentence Whh: ng = w*128 + g*32 + jl (jl = jh*16+l15)
      int kp = id & 127, ng = (id>>7)&1023, dir = id>>17;
      int w = ng>>7, g = (ng>>5)&3, jl = ng&31;
      int row = g*256 + w*32 + jl;
      const float* s = (dir ? Whh_b : Whh_f) + (size_t)row*256 + 2*kp;
      wWs[id] = pack2(s[0], s[1]);
    } else if ((id -= N4) < N5) {        // sentence Wih packed [dir][kp][j][g], 306 = 153 pairs
      int dir = id >= 156672; int r = id - dir*156672;
      int g = r & 3, j = (r>>2)&255, kp = r>>10;
      const float* s = (dir ? Wih_b : Wih_f) + (size_t)(g*256+j)*306 + 2*kp;
      wWihs[id] = pack2(s[0], s[1]);
    } else if ((id -= N5) < N6) {        // sentence bias sums [dir][j][g]
      int g = id & 3, j = (id>>2)&255, dir = id>>10;
      int row = g*256+j;
      wbss[id] = dir ? (bih_b[row]+bhh_b[row]) : (bih_f[row]+bhh_f[row]);
    } else if ((id -= N6) < N7) {        // Wo packed [kp][o]
      int o = id & 31, kp = id>>5;
      const float* s = Wo + (size_t)o*512 + 2*kp;
      wWo[id] = pack2(s[0], s[1]);
    } else { id -= N7;                   // bert = Xw[:,20:198,0] -> sent[:,128:306]
      int wg = id / 178, ii = id % 178;
      sent[(size_t)wg*SROW + 128 + ii] = X[(size_t)wg*9900 + (20+ii)*50];
    }
  }
}

// ---- word LSTM via MFMA: 128 blocks x 16 words, 8 waves, N=512 (wave: 16 j x 4 gates).
__global__ __launch_bounds__(512, 2) void k_word(
    const float* __restrict__ X, const float* __restrict__ h0w, const float* __restrict__ c0w,
    const uint32_t* __restrict__ wWsw, const uint32_t* __restrict__ wWxw,
    const float* __restrict__ wbsw, const uint32_t* __restrict__ wWlf,
    const float* __restrict__ bl, float* __restrict__ sent)
{
  __shared__ __align__(16) uint32_t lets[11520];      // [t20][m16][36] f16x2 (72 cols, 50 real)
  __shared__ __align__(16) uint16_t hbuf[2][2176];    // [m16][136]
  const int tid = threadIdx.x;
  const int wave = tid >> 6, lane = tid & 63;
  const int l15 = lane & 15, l4 = lane >> 4;
  const int wg0 = blockIdx.x * 16;

  uint4 Bh[4][4], Bx[4][2];
  #pragma unroll
  for (int g = 0; g < 4; ++g) {
    int ng = wave*64 + g*16 + l15;
    #pragma unroll
    for (int Kt = 0; Kt < 4; ++Kt) Bh[g][Kt] = *(const uint4*)(wWsw + ng*64 + Kt*16 + l4*4);
    #pragma unroll
    for (int Kt = 0; Kt < 2; ++Kt) Bx[g][Kt] = *(const uint4*)(wWxw + ng*32 + Kt*16 + l4*4);
  }
  for (int i = tid; i < 11520; i += 512) {
    int c = i % 36, mt = i / 36; int m = mt & 15, t = mt >> 4;
    lets[i] = (c < 25) ? pack2(X[(size_t)(wg0+m)*9900 + t*50 + 2*c],
                               X[(size_t)(wg0+m)*9900 + t*50 + 2*c + 1]) : 0u;
  }
  for (int i = tid; i < 2048; i += 512) {
    int m = i >> 7, k = i & 127;
    hbuf[0][m*136 + k] = f16b(h0w[(size_t)(wg0+m)*128 + k]);
  }
  const float4 bs = *(const float4*)(wbsw + (wave*16 + l15)*4);
  float cr[4];
  #pragma unroll
  for (int r = 0; r < 4; ++r) cr[r] = c0w[(size_t)(wg0 + l4*4 + r)*128 + wave*16 + l15];
  __syncthreads();

  uint16_t* hc = hbuf[0];
  uint16_t* hn = hbuf[1];
  const uint16_t* lp = (const uint16_t*)lets;
  #pragma unroll 1
  for (int t = 0; t < 20; ++t) {
    f32x4_t acc[4];
    acc[0] = (f32x4_t){bs.x,bs.x,bs.x,bs.x};
    acc[1] = (f32x4_t){bs.y,bs.y,bs.y,bs.y};
    acc[2] = (f32x4_t){bs.z,bs.z,bs.z,bs.z};
    acc[3] = (f32x4_t){bs.w,bs.w,bs.w,bs.w};
    #pragma unroll
    for (int Kt = 0; Kt < 2; ++Kt) {
      uint4 av = *(const uint4*)(lp + (t*16 + l15)*72 + Kt*32 + l4*8);
      half8_t a = __builtin_bit_cast(half8_t, av);
      #pragma unroll
      for (int g = 0; g < 4; ++g)
        acc[g] = __builtin_amdgcn_mfma_f32_16x16x32_f16(a, __builtin_bit_cast(half8_t, Bx[g][Kt]), acc[g], 0,0,0);
    }
    #pragma unroll
    for (int Kt = 0; Kt < 4; ++Kt) {
      uint4 av = *(const uint4*)(hc + l15*136 + Kt*32 + l4*8);
      half8_t a = __builtin_bit_cast(half8_t, av);
      #pragma unroll
      for (int g = 0; g < 4; ++g)
        acc[g] = __builtin_amdgcn_mfma_f32_16x16x32_f16(a, __builtin_bit_cast(half8_t, Bh[g][Kt]), acc[g], 0,0,0);
    }
    #pragma unroll
    for (int r = 0; r < 4; ++r) {
      float cc = sigm(acc[1][r])*cr[r] + sigm(acc[0][r])*tanhf_(acc[2][r]);
      cr[r] = cc;
      float hh = sigm(acc[3][r])*tanhf_(cc);
      hn[(l4*4+r)*136 + wave*16 + l15] = f16b(hh);
    }
    uint16_t* tp = hc; hc = hn; hn = tp;
    __syncthreads();
  }
  uint4 Bl[4];
  #pragma unroll
  for (int Kt = 0; Kt < 4; ++Kt) Bl[Kt] = *(const uint4*)(wWlf + (wave*16 + l15)*64 + Kt*16 + l4*4);
  f32x4_t a2 = (f32x4_t){0.f,0.f,0.f,0.f};
  #pragma unroll
  for (int Kt = 0; Kt < 4; ++Kt) {
    uint4 av = *(const uint4*)(hc + l15*136 + Kt*32 + l4*8);
    a2 = __builtin_amdgcn_mfma_f32_16x16x32_f16(__builtin_bit_cast(half8_t, av),
                                                __builtin_bit_cast(half8_t, Bl[Kt]), a2, 0,0,0);
  }
  const float blv = bl[wave*16 + l15];
  #pragma unroll
  for (int r = 0; r < 4; ++r)
    sent[(size_t)(wg0 + l4*4 + r)*SROW + wave*16 + l15] = a2[r] + blv;
}

// ---- sentence xg GEMM -> xgq in srec per-pass-contiguous layout (R4-verified):
// uint2 idx = ((((dir*64+tt)*2+half)*8+w)*2+jh)*256 + l15*16 + l4*4 + r
__global__ __launch_bounds__(256) void k_sxg(
    const float* __restrict__ sent, const uint32_t* __restrict__ Wihs,
    const float* __restrict__ bss, uint2* __restrict__ xgq)
{
  __shared__ uint32_t x16[153*8];
  const int tid = threadIdx.x;
  const int dir = blockIdx.x >> 8, rg = blockIdx.x & 255;
  for (int i = tid; i < 153*8; i += 256) {
    int r = i & 7, kp = i >> 3;
    int ot = rg*8 + r; int b = ot >> 6, tt = ot & 63;
    int si = dir ? (63 - tt) : tt;
    const float* s = sent + (size_t)(b*64 + si)*SROW + 2*kp;
    x16[kp*8 + r] = pack2(s[0], s[1]);
  }
  __syncthreads();
  const int j = tid;
  float acc[8][4];
  {
    const float4 b4 = *(const float4*)(bss + (dir*256 + j)*4);
    #pragma unroll
    for (int r = 0; r < 8; ++r) { acc[r][0]=b4.x; acc[r][1]=b4.y; acc[r][2]=b4.z; acc[r][3]=b4.w; }
  }
  for (int kp = 0; kp < 153; ++kp) {
    uint4 wv = *(const uint4*)(Wihs + ((size_t)(dir*153 + kp)*256 + j)*4);
    uint4 xa = *(const uint4*)(x16 + kp*8);
    uint4 xb = *(const uint4*)(x16 + kp*8 + 4);
    uint32_t wa[4] = {wv.x,wv.y,wv.z,wv.w};
    uint32_t xs[8] = {xa.x,xa.y,xa.z,xa.w,xb.x,xb.y,xb.z,xb.w};
    #pragma unroll
    for (int r = 0; r < 8; ++r)
      #pragma unroll
      for (int g = 0; g < 4; ++g) acc[r][g] = fdot2(wa[g], xs[r], acc[r][g]);
  }
  const int w = j >> 5, jh2 = (j >> 4) & 1, l15j = j & 15;
  #pragma unroll
  for (int r = 0; r < 8; ++r) {
    int ot = rg*8 + r; int b = ot >> 6, tt = ot & 63;
    int half = b >> 4, l4m = (b >> 2) & 3, rm = b & 3;
    uint2 v; v.x = pack2(acc[r][0], acc[r][1]); v.y = pack2(acc[r][2], acc[r][3]);
    size_t idx = ((((size_t)(dir*64 + tt)*2 + half)*8 + w)*2 + jh2)*256 + l15j*16 + l4m*4 + rm;
    xgq[idx] = v;
  }
}

// ---- sentence recurrence: grid 4 = (dir, batch-half M=16). 8 waves, 2/SIMD, 256 unified regs.
// MERGED single pass: acc[8] (Nt = g*2+jh), A-frags read ONCE per step (8 ds_reads),
// acc seeded from xg at step start (xg regs die early), next-step xg prefetched
// across the lgkm-only barrier (vmcnt flies).
__global__ __launch_bounds__(512, 2) void k_srec(
    const uint32_t* __restrict__ Ws, const float* __restrict__ h0f, const float* __restrict__ c0f,
    const float* __restrict__ h0b, const float* __restrict__ c0b,
    const uint2* __restrict__ xgq, uint16_t* __restrict__ outfb)
{
  extern __shared__ char smem[];               // [0,131072) B-frags, then h dbuf 2x[16][HSTR]
  uint16_t* h16a = (uint16_t*)(smem + 131072);
  uint16_t* h16b = h16a + 16*HSTR;
  const int tid = threadIdx.x;
  const int wave = tid >> 6, lane = tid & 63;
  const int dir = blockIdx.x >> 1, half = blockIdx.x & 1, m0 = half * 16;
  const int l15 = lane & 15, l4 = lane >> 4;

  uint4 Breg[8][6];
  #pragma unroll
  for (int Nt = 0; Nt < 8; ++Nt) {
    #pragma unroll
    for (int Kt = 0; Kt < 8; ++Kt) {
      int ng = wave*128 + Nt*16 + l15;
      uint4 v = *(const uint4*)(Ws + (size_t)(dir*1024 + ng)*128 + Kt*16 + l4*4);
      if (Kt < 6) Breg[Nt][Kt] = v;
      else *(uint4*)(smem + (((wave*16 + Nt*2 + (Kt-6))*64 + lane)*16)) = v;
    }
  }
  {
    const float* h0 = dir ? h0b : h0f;
    for (int i = tid; i < 16*256; i += 512) {
      int m = i >> 8, k = i & 255;
      h16a[m*HSTR + k] = f16b(h0[(size_t)(m0+m)*256 + k]);
    }
  }
  float cr[2][4];
  {
    const float* c0 = dir ? c0b : c0f;
    #pragma unroll
    for (int jh = 0; jh < 2; ++jh)
      #pragma unroll
      for (int r = 0; r < 4; ++r)
        cr[jh][r] = c0[(size_t)(m0 + l4*4 + r)*256 + wave*32 + jh*16 + l15];
  }
  __syncthreads();

  // uniform bases (SGPR) + per-lane 32-bit offsets
  const char* xbase = (const char*)xgq + (size_t)dir*4194304 + half*32768;
  const uint32_t xlane = wave*4096 + l15*128 + l4*32;
  const int s0 = dir ? 63 : 0;
  const int sdelta = dir ? -65536 : 65536;
  const char* obase = (const char*)outfb + (size_t)s0*65536 + half*32768 + dir*16384;
  const uint32_t olane = (l4*4)*512 + wave*64 + l15*2;
  const uint32_t aoff = l15*HSTR + l4*8;       // A-frag offset (halves) within h block

  uint16_t* hc = h16a;
  uint16_t* hn = h16b;

  // prefetch t=0 xg (4 x uint4: [jh0: +0,+16][jh1: +2048,+2064])
  uint4 p0 = *(const uint4*)(xbase + xlane);
  uint4 p1 = *(const uint4*)(xbase + xlane + 16);
  uint4 p2 = *(const uint4*)(xbase + xlane + 2048);
  uint4 p3 = *(const uint4*)(xbase + xlane + 2064);

  #pragma unroll 1
  for (int t = 0; t < 64; ++t) {
    // seed accumulators from xg; p regs die here. Nt = g*2 + jh.
    f32x4_t acc[8];
    acc[0] = (f32x4_t){lo16(p0.x), lo16(p0.z), lo16(p1.x), lo16(p1.z)};  // i,  jh0
    acc[2] = (f32x4_t){hi16(p0.x), hi16(p0.z), hi16(p1.x), hi16(p1.z)};  // f,  jh0
    acc[4] = (f32x4_t){lo16(p0.y), lo16(p0.w), lo16(p1.y), lo16(p1.w)};  // g,  jh0
    acc[6] = (f32x4_t){hi16(p0.y), hi16(p0.w), hi16(p1.y), hi16(p1.w)};  // o,  jh0
    acc[1] = (f32x4_t){lo16(p2.x), lo16(p2.z), lo16(p3.x), lo16(p3.z)};  // i,  jh1
    acc[3] = (f32x4_t){hi16(p2.x), hi16(p2.z), hi16(p3.x), hi16(p3.z)};  // f,  jh1
    acc[5] = (f32x4_t){lo16(p2.y), lo16(p2.w), lo16(p3.y), lo16(p3.w)};  // g,  jh1
    acc[7] = (f32x4_t){hi16(p2.y), hi16(p2.w), hi16(p3.y), hi16(p3.w)};  // o,  jh1

    #pragma unroll
    for (int Kt = 0; Kt < 8; ++Kt) {
      uint4 av = *(const uint4*)(hc + aoff + Kt*32);     // ONE A read per Kt (shared by 8 MFMAs)
      half8_t a = __builtin_bit_cast(half8_t, av);
      #pragma unroll
      for (int Nt = 0; Nt < 8; ++Nt) {
        uint4 bv;
        if (Kt < 6) bv = Breg[Nt][Kt];
        else bv = *(const uint4*)(smem + (((wave*16 + Nt*2 + (Kt-6))*64 + lane)*16));
        acc[Nt] = __builtin_amdgcn_mfma_f32_16x16x32_f16(a, __builtin_bit_cast(half8_t, bv), acc[Nt], 0,0,0);
      }
    }

    // prefetch next step's xg (issued before barrier; vmcnt not drained by it)
    p0 = *(const uint4*)(xbase + xlane + 65536);
    p1 = *(const uint4*)(xbase + xlane + 65536 + 16);
    p2 = *(const uint4*)(xbase + xlane + 65536 + 2048);
    p3 = *(const uint4*)(xbase + xlane + 65536 + 2064);

    #pragma unroll
    for (int jh = 0; jh < 2; ++jh) {
      #pragma unroll
      for (int r = 0; r < 4; ++r) {
        float gi = acc[0+jh][r], gf = acc[2+jh][r], gg = acc[4+jh][r], go = acc[6+jh][r];
        // fused-denominator LSTM update: 5 exp + 2 rcp
        float ef = __expf(-gf), ei = __expf(-gi), eg = __expf(-2.f*gg);
        float pef = 1.f + ef, pei = 1.f + ei, peg = 1.f + eg;
        float num = cr[jh][r]*pei*peg + (1.f - eg)*pef;
        float cc  = num * __builtin_amdgcn_rcpf(pef*pei*peg);
        cr[jh][r] = cc;
        float ec = __expf(-2.f*cc), eo = __expf(-go);
        float hh = (1.f - ec) * __builtin_amdgcn_rcpf((1.f + ec)*(1.f + eo));
        uint16_t hb = f16b(hh);
        hn[(l4*4+r)*HSTR + wave*32 + jh*16 + l15] = hb;
        *(uint16_t*)(obase + olane + r*512 + jh*32) = hb;
      }
    }
    { uint16_t* tp = hc; hc = hn; hn = tp; }
    xbase += 65536;
    obase += sdelta;
    // only this step's LDS writes must drain; global loads/stores fly across
    asm volatile("s_waitcnt lgkmcnt(0)\ns_barrier" ::: "memory");
  }
}

// ---- tags + softmax (reads the R4-verified outfb layout)
__global__ __launch_bounds__(256) void k_tags(
    const uint16_t* __restrict__ outfb, const uint32_t* __restrict__ Wo16,
    const float* __restrict__ bo, float* __restrict__ out)
{
  __shared__ uint32_t xr[8*256];
  const int tid = threadIdx.x;
  const int w0 = blockIdx.x * 8;
  const uint32_t* src = (const uint32_t*)outfb;
  for (int i = tid; i < 2048; i += 256) {
    int w = i >> 8, kp = i & 255;                // kp: u32 over k = dir*256 + wave*32 + jh*16 + l15
    int widx = w0 + w;
    int s = widx & 63, q = widx >> 6;
    int half = q >> 4, m = q & 15;
    int dir = kp >> 7, wv = (kp >> 4) & 7, jh = (kp >> 3) & 1, l15h = kp & 7;
    xr[i] = src[s*16384 + half*8192 + dir*4096 + m*128 + wv*16 + jh*8 + l15h];
  }
  __syncthreads();
  const int o = tid & 31, w = tid >> 5;
  float a = bo[o];
  for (int kp = 0; kp < 256; ++kp)
    a = fdot2(Wo16[kp*32 + o], xr[w*256 + kp], a);
  float mx = a;
  #pragma unroll
  for (int off = 16; off; off >>= 1) mx = fmaxf(mx, __shfl_xor(mx, off, 32));
  float e = __expf(a - mx);
  float ssum = e;
  #pragma unroll
  for (int off = 16; off; off >>= 1) ssum += __shfl_xor(ssum, off, 32);
  out[(size_t)(w0+w)*32 + o] = e * __builtin_amdgcn_rcpf(ssum);
}

extern "C" void kernel_launch(void* const* d_in, const int* in_sizes, int n_in,
                              void* d_out, int out_size, void* d_ws, size_t ws_size,
                              hipStream_t stream) {
  const float* X     = (const float*)d_in[0];
  const float* h0w   = (const float*)d_in[1];
  const float* c0w   = (const float*)d_in[2];
  const float* h0f   = (const float*)d_in[3];
  const float* c0f   = (const float*)d_in[4];
  const float* h0b   = (const float*)d_in[5];
  const float* c0b   = (const float*)d_in[6];
  const float* Wih_w = (const float*)d_in[7];
  const float* Whh_w = (const float*)d_in[8];
  const float* bih_w = (const float*)d_in[9];
  const float* bhh_w = (const float*)d_in[10];
  const float* Wl    = (const float*)d_in[11];
  const float* bl    = (const float*)d_in[12];
  const float* Wih_f = (const float*)d_in[13];
  const float* Whh_f = (const float*)d_in[14];
  const float* bih_f = (const float*)d_in[15];
  const float* bhh_f = (const float*)d_in[16];
  const float* Wih_b = (const float*)d_in[17];
  const float* Whh_b = (const float*)d_in[18];
  const float* bih_b = (const float*)d_in[19];
  const float* bhh_b = (const float*)d_in[20];
  const float* Wo    = (const float*)d_in[21];
  const float* bo    = (const float*)d_in[22];

  char* ws = (char*)d_ws;
  uint32_t* wWsw  = (uint32_t*)(ws + 0);          // 131072 B
  uint32_t* wWxw  = (uint32_t*)(ws + 131072);     // 65536 B
  uint32_t* wWlf  = (uint32_t*)(ws + 196608);     // 32768 B
  float*    wbsw  = (float*)   (ws + 229376);     // 2048 B
  uint32_t* wWs   = (uint32_t*)(ws + 231424);     // 1048576 B
  uint32_t* wWihs = (uint32_t*)(ws + 1280000);    // 1253376 B
  float*    wbss  = (float*)   (ws + 2533376);    // 8192 B
  uint32_t* wWo   = (uint32_t*)(ws + 2541568);    // 32768 B
  float*    sent  = (float*)   (ws + 2574336);    // 2523136 B
  uint2*    xgq   = (uint2*)   (ws + 5097472);    // 8388608 B
  uint16_t* outfb = (uint16_t*)(ws + 13486080);   // 2097152 B -> end ~15.6 MB

  hipFuncSetAttribute((const void*)k_srec, hipFuncAttributeMaxDynamicSharedMemorySize, 148992);

  k_prep<<<2048, 256, 0, stream>>>(X, Wih_w, Whh_w, bih_w, bhh_w, Wl, Wih_f, Whh_f, bih_f, bhh_f,
                                   Wih_b, Whh_b, bih_b, bhh_b, Wo,
                                   wWsw, wWxw, wWlf, wbsw, wWs, wWihs, wbss, wWo, sent);
  k_word<<<128, 512, 0, stream>>>(X, h0w, c0w, wWsw, wWxw, wbsw, wWlf, bl, sent);
  k_sxg<<<512, 256, 0, stream>>>(sent, wWihs, wbss, xgq);
  k_srec<<<4, 512, 148992, stream>>>(wWs, h0f, c0f, h0b, c0b, xgq, outfb);
  k_tags<<<256, 256, 0, stream>>>(outfb, wWo, bo, (float*)d_out);
}

// Round 8
// 306.332 us; speedup vs baseline: 1.5115x; 1.0144x over previous
//
#include <hip/hip_runtime.h>
#include <cstdint>
#include <cstddef>

#define DI static __device__ __forceinline__

using half_t  = _Float16;
using half2_t = __attribute__((ext_vector_type(2))) _Float16;
using half8_t = __attribute__((ext_vector_type(8))) _Float16;
using f32x4_t = __attribute__((ext_vector_type(4))) float;

DI uint32_t pack2(float a, float b){ half2_t h; h[0]=(half_t)a; h[1]=(half_t)b; return __builtin_bit_cast(uint32_t,h); }
DI uint16_t f16b(float a){ return __builtin_bit_cast(uint16_t,(half_t)a); }
DI float lo16(uint32_t u){ half2_t h=__builtin_bit_cast(half2_t,u); return (float)h[0]; }
DI float hi16(uint32_t u){ half2_t h=__builtin_bit_cast(half2_t,u); return (float)h[1]; }
DI float fdot2(uint32_t w, uint32_t x, float acc){
  return __builtin_amdgcn_fdot2(__builtin_bit_cast(half2_t,w), __builtin_bit_cast(half2_t,x), acc, false);
}
DI float sigm(float x){ return __builtin_amdgcn_rcpf(1.f + __expf(-x)); }
DI float tanhf_(float x){ return 1.f - 2.f*__builtin_amdgcn_rcpf(__expf(2.f*x)+1.f); }

// problem sizes: B=32 S=64 NW=2048 T=198 L=50 WLEN=20 BERT=178 Hs=128 Hm=256 Din=306 O=32
#define SROW 308   // sentences_in row stride (306 used)
#define HSTR 280   // k_srec h-row stride in halves (560 B = free 2-way banks)

// prep job sizes
#define N0 32768   // word Whh MFMA-B frags [ng512][kp64]
#define N1 16384   // word Wih MFMA-B frags [ng512][kp32] (k=50 zero-padded to 64)
#define N2 8192    // Wl B-frags [d128][kp64]
#define N3 512     // word bias sum [j128][g4]
#define N4 262144  // sent Whh B-frag layout [dir][ng1024][kp128], ng = w*128 + g*32 + jh*16 + jl
#define N5 313344  // sent Wih f16x2 [dir][kp153][j256][g4]
#define N6 2048    // sent bias sum [dir][j256][g4]
#define N7 8192    // Wo f16x2 [kp256][o32]
#define N8 364544  // bert -> sent[:,128:306]
#define NTOT (N0+N1+N2+N3+N4+N5+N6+N7+N8)

__global__ void k_prep(const float* __restrict__ X,
                       const float* __restrict__ Wih_w, const float* __restrict__ Whh_w,
                       const float* __restrict__ bih_w, const float* __restrict__ bhh_w,
                       const float* __restrict__ Wl,
                       const float* __restrict__ Wih_f, const float* __restrict__ Whh_f,
                       const float* __restrict__ bih_f, const float* __restrict__ bhh_f,
                       const float* __restrict__ Wih_b, const float* __restrict__ Whh_b,
                       const float* __restrict__ bih_b, const float* __restrict__ bhh_b,
                       const float* __restrict__ Wo,
                       uint32_t* __restrict__ wWsw, uint32_t* __restrict__ wWxw,
                       uint32_t* __restrict__ wWlf, float* __restrict__ wbsw,
                       uint32_t* __restrict__ wWs, uint32_t* __restrict__ wWihs,
                       float* __restrict__ wbss, uint32_t* __restrict__ wWo,
                       float* __restrict__ sent)
{
  for (int i = blockIdx.x*blockDim.x + threadIdx.x; i < NTOT; i += gridDim.x*blockDim.x) {
    int id = i;
    if (id < N0) {                       // word Whh B-frags: ng = w*64+g*16+jl -> row g*128+w*16+jl
      int kp = id & 63, ng = id >> 6;
      int w = ng>>6, g = (ng>>4)&3, jl = ng&15;
      const float* s = Whh_w + (size_t)(g*128 + w*16 + jl)*128 + 2*kp;
      wWsw[id] = pack2(s[0], s[1]);
    } else if ((id -= N0) < N1) {        // word Wih B-frags, k padded 50->64
      int kp = id & 31, ng = id >> 5;
      int w = ng>>6, g = (ng>>4)&3, jl = ng&15;
      if (kp < 25) {
        const float* s = Wih_w + (size_t)(g*128 + w*16 + jl)*50 + 2*kp;
        wWxw[id] = pack2(s[0], s[1]);
      } else wWxw[id] = 0u;
    } else if ((id -= N1) < N2) {        // Wl B-frags [d][kp]
      int kp = id & 63, d = id >> 6;
      const float* s = Wl + (size_t)d*128 + 2*kp;
      wWlf[id] = pack2(s[0], s[1]);
    } else if ((id -= N2) < N3) {        // word bias sum [j][g]
      int g = id & 3, j = id>>2;
      wbsw[id] = bih_w[g*128+j] + bhh_w[g*128+j];
    } else if ((id -= N3) < N4) {        // sentence Whh: ng = w*128 + g*32 + jl (jl = jh*16+l15)
      int kp = id & 127, ng = (id>>7)&1023, dir = id>>17;
      int w = ng>>7, g = (ng>>5)&3, jl = ng&31;
      int row = g*256 + w*32 + jl;
      const float* s = (dir ? Whh_b : Whh_f) + (size_t)row*256 + 2*kp;
      wWs[id] = pack2(s[0], s[1]);
    } else if ((id -= N4) < N5) {        // sentence Wih packed [dir][kp][j][g], 306 = 153 pairs
      int dir = id >= 156672; int r = id - dir*156672;
      int g = r & 3, j = (r>>2)&255, kp = r>>10;
      const float* s = (dir ? Wih_b : Wih_f) + (size_t)(g*256+j)*306 + 2*kp;
      wWihs[id] = pack2(s[0], s[1]);
    } else if ((id -= N5) < N6) {        // sentence bias sums [dir][j][g]
      int g = id & 3, j = (id>>2)&255, dir = id>>10;
      int row = g*256+j;
      wbss[id] = dir ? (bih_b[row]+bhh_b[row]) : (bih_f[row]+bhh_f[row]);
    } else if ((id -= N6) < N7) {        // Wo packed [kp][o]
      int o = id & 31, kp = id>>5;
      const float* s = Wo + (size_t)o*512 + 2*kp;
      wWo[id] = pack2(s[0], s[1]);
    } else { id -= N7;                   // bert = Xw[:,20:198,0] -> sent[:,128:306]
      int wg = id / 178, ii = id % 178;
      sent[(size_t)wg*SROW + 128 + ii] = X[(size_t)wg*9900 + (20+ii)*50];
    }
  }
}

// ---- word LSTM via MFMA: 128 blocks x 16 words, 8 waves, N=512 (wave: 16 j x 4 gates).
__global__ __launch_bounds__(512, 2) void k_word(
    const float* __restrict__ X, const float* __restrict__ h0w, const float* __restrict__ c0w,
    const uint32_t* __restrict__ wWsw, const uint32_t* __restrict__ wWxw,
    const float* __restrict__ wbsw, const uint32_t* __restrict__ wWlf,
    const float* __restrict__ bl, float* __restrict__ sent)
{
  __shared__ __align__(16) uint32_t lets[11520];      // [t20][m16][36] f16x2 (72 cols, 50 real)
  __shared__ __align__(16) uint16_t hbuf[2][2176];    // [m16][136]
  const int tid = threadIdx.x;
  const int wave = tid >> 6, lane = tid & 63;
  const int l15 = lane & 15, l4 = lane >> 4;
  const int wg0 = blockIdx.x * 16;

  uint4 Bh[4][4], Bx[4][2];
  #pragma unroll
  for (int g = 0; g < 4; ++g) {
    int ng = wave*64 + g*16 + l15;
    #pragma unroll
    for (int Kt = 0; Kt < 4; ++Kt) Bh[g][Kt] = *(const uint4*)(wWsw + ng*64 + Kt*16 + l4*4);
    #pragma unroll
    for (int Kt = 0; Kt < 2; ++Kt) Bx[g][Kt] = *(const uint4*)(wWxw + ng*32 + Kt*16 + l4*4);
  }
  for (int i = tid; i < 11520; i += 512) {
    int c = i % 36, mt = i / 36; int m = mt & 15, t = mt >> 4;
    lets[i] = (c < 25) ? pack2(X[(size_t)(wg0+m)*9900 + t*50 + 2*c],
                               X[(size_t)(wg0+m)*9900 + t*50 + 2*c + 1]) : 0u;
  }
  for (int i = tid; i < 2048; i += 512) {
    int m = i >> 7, k = i & 127;
    hbuf[0][m*136 + k] = f16b(h0w[(size_t)(wg0+m)*128 + k]);
  }
  const float4 bs = *(const float4*)(wbsw + (wave*16 + l15)*4);
  float cr[4];
  #pragma unroll
  for (int r = 0; r < 4; ++r) cr[r] = c0w[(size_t)(wg0 + l4*4 + r)*128 + wave*16 + l15];
  __syncthreads();

  uint16_t* hc = hbuf[0];
  uint16_t* hn = hbuf[1];
  const uint16_t* lp = (const uint16_t*)lets;
  #pragma unroll 1
  for (int t = 0; t < 20; ++t) {
    f32x4_t acc[4];
    acc[0] = (f32x4_t){bs.x,bs.x,bs.x,bs.x};
    acc[1] = (f32x4_t){bs.y,bs.y,bs.y,bs.y};
    acc[2] = (f32x4_t){bs.z,bs.z,bs.z,bs.z};
    acc[3] = (f32x4_t){bs.w,bs.w,bs.w,bs.w};
    #pragma unroll
    for (int Kt = 0; Kt < 2; ++Kt) {
      uint4 av = *(const uint4*)(lp + (t*16 + l15)*72 + Kt*32 + l4*8);
      half8_t a = __builtin_bit_cast(half8_t, av);
      #pragma unroll
      for (int g = 0; g < 4; ++g)
        acc[g] = __builtin_amdgcn_mfma_f32_16x16x32_f16(a, __builtin_bit_cast(half8_t, Bx[g][Kt]), acc[g], 0,0,0);
    }
    #pragma unroll
    for (int Kt = 0; Kt < 4; ++Kt) {
      uint4 av = *(const uint4*)(hc + l15*136 + Kt*32 + l4*8);
      half8_t a = __builtin_bit_cast(half8_t, av);
      #pragma unroll
      for (int g = 0; g < 4; ++g)
        acc[g] = __builtin_amdgcn_mfma_f32_16x16x32_f16(a, __builtin_bit_cast(half8_t, Bh[g][Kt]), acc[g], 0,0,0);
    }
    #pragma unroll
    for (int r = 0; r < 4; ++r) {
      float cc = sigm(acc[1][r])*cr[r] + sigm(acc[0][r])*tanhf_(acc[2][r]);
      cr[r] = cc;
      float hh = sigm(acc[3][r])*tanhf_(cc);
      hn[(l4*4+r)*136 + wave*16 + l15] = f16b(hh);
    }
    uint16_t* tp = hc; hc = hn; hn = tp;
    __syncthreads();
  }
  uint4 Bl[4];
  #pragma unroll
  for (int Kt = 0; Kt < 4; ++Kt) Bl[Kt] = *(const uint4*)(wWlf + (wave*16 + l15)*64 + Kt*16 + l4*4);
  f32x4_t a2 = (f32x4_t){0.f,0.f,0.f,0.f};
  #pragma unroll
  for (int Kt = 0; Kt < 4; ++Kt) {
    uint4 av = *(const uint4*)(hc + l15*136 + Kt*32 + l4*8);
    a2 = __builtin_amdgcn_mfma_f32_16x16x32_f16(__builtin_bit_cast(half8_t, av),
                                                __builtin_bit_cast(half8_t, Bl[Kt]), a2, 0,0,0);
  }
  const float blv = bl[wave*16 + l15];
  #pragma unroll
  for (int r = 0; r < 4; ++r)
    sent[(size_t)(wg0 + l4*4 + r)*SROW + wave*16 + l15] = a2[r] + blv;
}

// ---- sentence xg GEMM -> xgq in srec per-pass-contiguous layout (R4-verified):
// uint2 idx = ((((dir*64+tt)*2+half)*8+w)*2+jh)*256 + l15*16 + l4*4 + r
__global__ __launch_bounds__(256) void k_sxg(
    const float* __restrict__ sent, const uint32_t* __restrict__ Wihs,
    const float* __restrict__ bss, uint2* __restrict__ xgq)
{
  __shared__ uint32_t x16[153*8];
  const int tid = threadIdx.x;
  const int dir = blockIdx.x >> 8, rg = blockIdx.x & 255;
  for (int i = tid; i < 153*8; i += 256) {
    int r = i & 7, kp = i >> 3;
    int ot = rg*8 + r; int b = ot >> 6, tt = ot & 63;
    int si = dir ? (63 - tt) : tt;
    const float* s = sent + (size_t)(b*64 + si)*SROW + 2*kp;
    x16[kp*8 + r] = pack2(s[0], s[1]);
  }
  __syncthreads();
  const int j = tid;
  float acc[8][4];
  {
    const float4 b4 = *(const float4*)(bss + (dir*256 + j)*4);
    #pragma unroll
    for (int r = 0; r < 8; ++r) { acc[r][0]=b4.x; acc[r][1]=b4.y; acc[r][2]=b4.z; acc[r][3]=b4.w; }
  }
  for (int kp = 0; kp < 153; ++kp) {
    uint4 wv = *(const uint4*)(Wihs + ((size_t)(dir*153 + kp)*256 + j)*4);
    uint4 xa = *(const uint4*)(x16 + kp*8);
    uint4 xb = *(const uint4*)(x16 + kp*8 + 4);
    uint32_t wa[4] = {wv.x,wv.y,wv.z,wv.w};
    uint32_t xs[8] = {xa.x,xa.y,xa.z,xa.w,xb.x,xb.y,xb.z,xb.w};
    #pragma unroll
    for (int r = 0; r < 8; ++r)
      #pragma unroll
      for (int g = 0; g < 4; ++g) acc[r][g] = fdot2(wa[g], xs[r], acc[r][g]);
  }
  const int w = j >> 5, jh2 = (j >> 4) & 1, l15j = j & 15;
  #pragma unroll
  for (int r = 0; r < 8; ++r) {
    int ot = rg*8 + r; int b = ot >> 6, tt = ot & 63;
    int half = b >> 4, l4m = (b >> 2) & 3, rm = b & 3;
    uint2 v; v.x = pack2(acc[r][0], acc[r][1]); v.y = pack2(acc[r][2], acc[r][3]);
    size_t idx = ((((size_t)(dir*64 + tt)*2 + half)*8 + w)*2 + jh2)*256 + l15j*16 + l4m*4 + rm;
    xgq[idx] = v;
  }
}

// ---- sentence recurrence: grid 4 = (dir, batch-half M=16). 8 waves, 2/SIMD, 256 unified regs.
// Two MFMA passes (jh0 then jh1); jh0-output updates are INTERLEAVED into pass jh1
// (sched_group_barrier-pinned) so the trans/VALU chain hides under MFMA issue.
__global__ __launch_bounds__(512, 2) void k_srec(
    const uint32_t* __restrict__ Ws, const float* __restrict__ h0f, const float* __restrict__ c0f,
    const float* __restrict__ h0b, const float* __restrict__ c0b,
    const uint2* __restrict__ xgq, uint16_t* __restrict__ outfb)
{
  extern __shared__ char smem[];               // [0,131072) B-frags, then h dbuf 2x[16][HSTR]
  uint16_t* h16a = (uint16_t*)(smem + 131072);
  uint16_t* h16b = h16a + 16*HSTR;
  const int tid = threadIdx.x;
  const int wave = tid >> 6, lane = tid & 63;
  const int dir = blockIdx.x >> 1, half = blockIdx.x & 1, m0 = half * 16;
  const int l15 = lane & 15, l4 = lane >> 4;

  uint4 Breg[8][6];
  #pragma unroll
  for (int Nt = 0; Nt < 8; ++Nt) {
    #pragma unroll
    for (int Kt = 0; Kt < 8; ++Kt) {
      int ng = wave*128 + Nt*16 + l15;
      uint4 v = *(const uint4*)(Ws + (size_t)(dir*1024 + ng)*128 + Kt*16 + l4*4);
      if (Kt < 6) Breg[Nt][Kt] = v;
      else *(uint4*)(smem + (((wave*16 + Nt*2 + (Kt-6))*64 + lane)*16)) = v;
    }
  }
  {
    const float* h0 = dir ? h0b : h0f;
    for (int i = tid; i < 16*256; i += 512) {
      int m = i >> 8, k = i & 255;
      h16a[m*HSTR + k] = f16b(h0[(size_t)(m0+m)*256 + k]);
    }
  }
  float cr[2][4];
  {
    const float* c0 = dir ? c0b : c0f;
    #pragma unroll
    for (int jh = 0; jh < 2; ++jh)
      #pragma unroll
      for (int r = 0; r < 4; ++r)
        cr[jh][r] = c0[(size_t)(m0 + l4*4 + r)*256 + wave*32 + jh*16 + l15];
  }
  __syncthreads();

  const char* xbase = (const char*)xgq + (size_t)dir*4194304 + half*32768;
  const uint32_t xlane = wave*4096 + l15*128 + l4*32;
  const int s0 = dir ? 63 : 0;
  const int sdelta = dir ? -65536 : 65536;
  const char* obase = (const char*)outfb + (size_t)s0*65536 + half*32768 + dir*16384;
  const uint32_t olane = (l4*4)*512 + wave*64 + l15*2;
  const uint32_t aoff = l15*HSTR + l4*8;

  uint16_t* hc = h16a;
  uint16_t* hn = h16b;

  // one-output LSTM update (gate regs -> h f16 to LDS + global)
#define UPD1(JH, R, GI, GF, GG, GO) {                                         \
    float eo = __expf(-(GO));                       /* independent: early */  \
    float ef = __expf(-(GF)), ei = __expf(-(GI)), eg = __expf(-2.f*(GG));     \
    float pef = 1.f + ef, pei = 1.f + ei, peg = 1.f + eg;                     \
    float num = cr[JH][R]*pei*peg + (1.f - eg)*pef;                           \
    float cc  = num * __builtin_amdgcn_rcpf(pef*pei*peg);                     \
    cr[JH][R] = cc;                                                           \
    float ec = __expf(-2.f*cc);                                               \
    float hh = (1.f - ec) * __builtin_amdgcn_rcpf((1.f + ec)*(1.f + eo));     \
    uint16_t hb = f16b(hh);                                                   \
    hn[(l4*4+(R))*HSTR + wave*32 + (JH)*16 + l15] = hb;                       \
    *(uint16_t*)(obase + olane + (R)*512 + (JH)*32) = hb;                     \
  }

  // prefetch t=0 xg
  uint4 p0 = *(const uint4*)(xbase + xlane);
  uint4 p1 = *(const uint4*)(xbase + xlane + 16);
  uint4 p2 = *(const uint4*)(xbase + xlane + 2048);
  uint4 p3 = *(const uint4*)(xbase + xlane + 2064);

  #pragma unroll 1
  for (int t = 0; t < 64; ++t) {
    // seed accumulators from xg (Nt = g*2 + jh)
    f32x4_t acc[8];
    acc[0] = (f32x4_t){lo16(p0.x), lo16(p0.z), lo16(p1.x), lo16(p1.z)};  // i,  jh0
    acc[2] = (f32x4_t){hi16(p0.x), hi16(p0.z), hi16(p1.x), hi16(p1.z)};  // f,  jh0
    acc[4] = (f32x4_t){lo16(p0.y), lo16(p0.w), lo16(p1.y), lo16(p1.w)};  // g,  jh0
    acc[6] = (f32x4_t){hi16(p0.y), hi16(p0.w), hi16(p1.y), hi16(p1.w)};  // o,  jh0
    acc[1] = (f32x4_t){lo16(p2.x), lo16(p2.z), lo16(p3.x), lo16(p3.z)};  // i,  jh1
    acc[3] = (f32x4_t){hi16(p2.x), hi16(p2.z), hi16(p3.x), hi16(p3.z)};  // f,  jh1
    acc[5] = (f32x4_t){lo16(p2.y), lo16(p2.w), lo16(p3.y), lo16(p3.w)};  // g,  jh1
    acc[7] = (f32x4_t){hi16(p2.y), hi16(p2.w), hi16(p3.y), hi16(p3.w)};  // o,  jh1

    // ---- PASS 0: jh0 MFMAs (Nt even)
    __builtin_amdgcn_s_setprio(1);
    #pragma unroll
    for (int Kt = 0; Kt < 8; ++Kt) {
      uint4 av = *(const uint4*)(hc + aoff + Kt*32);
      half8_t a = __builtin_bit_cast(half8_t, av);
      #pragma unroll
      for (int g = 0; g < 4; ++g) {
        const int Nt = g*2;
        uint4 bv;
        if (Kt < 6) bv = Breg[Nt][Kt];
        else bv = *(const uint4*)(smem + (((wave*16 + Nt*2 + (Kt-6))*64 + lane)*16));
        acc[Nt] = __builtin_amdgcn_mfma_f32_16x16x32_f16(a, __builtin_bit_cast(half8_t, bv), acc[Nt], 0,0,0);
      }
    }
    __builtin_amdgcn_s_setprio(0);

    // ---- PASS 1: jh1 MFMAs interleaved with jh0 updates (one update per 2 Kt)
    #pragma unroll
    for (int Kt = 0; Kt < 8; ++Kt) {
      uint4 av = *(const uint4*)(hc + aoff + Kt*32);
      half8_t a = __builtin_bit_cast(half8_t, av);
      #pragma unroll
      for (int g = 0; g < 4; ++g) {
        const int Nt = g*2 + 1;
        uint4 bv;
        if (Kt < 6) bv = Breg[Nt][Kt];
        else bv = *(const uint4*)(smem + (((wave*16 + Nt*2 + (Kt-6))*64 + lane)*16));
        acc[Nt] = __builtin_amdgcn_mfma_f32_16x16x32_f16(a, __builtin_bit_cast(half8_t, bv), acc[Nt], 0,0,0);
      }
      if (Kt & 1) {
        const int r = Kt >> 1;
        UPD1(0, r, acc[0][r], acc[2][r], acc[4][r], acc[6][r]);
        // pin: 8 MFMAs (2 Kt groups) then ~44 VALU (the update) per repeat
        __builtin_amdgcn_sched_group_barrier(0x008, 8, 0);   // MFMA
        __builtin_amdgcn_sched_group_barrier(0x002, 44, 0);  // VALU/trans
      }
    }

    // prefetch next step's xg (flies across the lgkm-only barrier)
    p0 = *(const uint4*)(xbase + xlane + 65536);
    p1 = *(const uint4*)(xbase + xlane + 65536 + 16);
    p2 = *(const uint4*)(xbase + xlane + 65536 + 2048);
    p3 = *(const uint4*)(xbase + xlane + 65536 + 2064);

    // ---- jh1 updates (exposed tail)
    #pragma unroll
    for (int r = 0; r < 4; ++r)
      UPD1(1, r, acc[1][r], acc[3][r], acc[5][r], acc[7][r]);

    { uint16_t* tp = hc; hc = hn; hn = tp; }
    xbase += 65536;
    obase += sdelta;
    asm volatile("s_waitcnt lgkmcnt(0)\ns_barrier" ::: "memory");
  }
#undef UPD1
}

// ---- tags + softmax (reads the R4-verified outfb layout)
__global__ __launch_bounds__(256) void k_tags(
    const uint16_t* __restrict__ outfb, const uint32_t* __restrict__ Wo16,
    const float* __restrict__ bo, float* __restrict__ out)
{
  __shared__ uint32_t xr[8*256];
  const int tid = threadIdx.x;
  const int w0 = blockIdx.x * 8;
  const uint32_t* src = (const uint32_t*)outfb;
  for (int i = tid; i < 2048; i += 256) {
    int w = i >> 8, kp = i & 255;                // kp: u32 over k = dir*256 + wave*32 + jh*16 + l15
    int widx = w0 + w;
    int s = widx & 63, q = widx >> 6;
    int half = q >> 4, m = q & 15;
    int dir = kp >> 7, wv = (kp >> 4) & 7, jh = (kp >> 3) & 1, l15h = kp & 7;
    xr[i] = src[s*16384 + half*8192 + dir*4096 + m*128 + wv*16 + jh*8 + l15h];
  }
  __syncthreads();
  const int o = tid & 31, w = tid >> 5;
  float a = bo[o];
  for (int kp = 0; kp < 256; ++kp)
    a = fdot2(Wo16[kp*32 + o], xr[w*256 + kp], a);
  float mx = a;
  #pragma unroll
  for (int off = 16; off; off >>= 1) mx = fmaxf(mx, __shfl_xor(mx, off, 32));
  float e = __expf(a - mx);
  float ssum = e;
  #pragma unroll
  for (int off = 16; off; off >>= 1) ssum += __shfl_xor(ssum, off, 32);
  out[(size_t)(w0+w)*32 + o] = e * __builtin_amdgcn_rcpf(ssum);
}

extern "C" void kernel_launch(void* const* d_in, const int* in_sizes, int n_in,
                              void* d_out, int out_size, void* d_ws, size_t ws_size,
                              hipStream_t stream) {
  const float* X     = (const float*)d_in[0];
  const float* h0w   = (const float*)d_in[1];
  const float* c0w   = (const float*)d_in[2];
  const float* h0f   = (const float*)d_in[3];
  const float* c0f   = (const float*)d_in[4];
  const float* h0b   = (const float*)d_in[5];
  const float* c0b   = (const float*)d_in[6];
  const float* Wih_w = (const float*)d_in[7];
  const float* Whh_w = (const float*)d_in[8];
  const float* bih_w = (const float*)d_in[9];
  const float* bhh_w = (const float*)d_in[10];
  const float* Wl    = (const float*)d_in[11];
  const float* bl    = (const float*)d_in[12];
  const float* Wih_f = (const float*)d_in[13];
  const float* Whh_f = (const float*)d_in[14];
  const float* bih_f = (const float*)d_in[15];
  const float* bhh_f = (const float*)d_in[16];
  const float* Wih_b = (const float*)d_in[17];
  const float* Whh_b = (const float*)d_in[18];
  const float* bih_b = (const float*)d_in[19];
  const float* bhh_b = (const float*)d_in[20];
  const float* Wo    = (const float*)d_in[21];
  const float* bo    = (const float*)d_in[22];

  char* ws = (char*)d_ws;
  uint32_t* wWsw  = (uint32_t*)(ws + 0);          // 131072 B
  uint32_t* wWxw  = (uint32_t*)(ws + 131072);     // 65536 B
  uint32_t* wWlf  = (uint32_t*)(ws + 196608);     // 32768 B
  float*    wbsw  = (float*)   (ws + 229376);     // 2048 B
  uint32_t* wWs   = (uint32_t*)(ws + 231424);     // 1048576 B
  uint32_t* wWihs = (uint32_t*)(ws + 1280000);    // 1253376 B
  float*    wbss  = (float*)   (ws + 2533376);    // 8192 B
  uint32_t* wWo   = (uint32_t*)(ws + 2541568);    // 32768 B
  float*    sent  = (float*)   (ws + 2574336);    // 2523136 B
  uint2*    xgq   = (uint2*)   (ws + 5097472);    // 8388608 B
  uint16_t* outfb = (uint16_t*)(ws + 13486080);   // 2097152 B -> end ~15.6 MB

  hipFuncSetAttribute((const void*)k_srec, hipFuncAttributeMaxDynamicSharedMemorySize, 148992);

  k_prep<<<2048, 256, 0, stream>>>(X, Wih_w, Whh_w, bih_w, bhh_w, Wl, Wih_f, Whh_f, bih_f, bhh_f,
                                   Wih_b, Whh_b, bih_b, bhh_b, Wo,
                                   wWsw, wWxw, wWlf, wbsw, wWs, wWihs, wbss, wWo, sent);
  k_word<<<128, 512, 0, stream>>>(X, h0w, c0w, wWsw, wWxw, wbsw, wWlf, bl, sent);
  k_sxg<<<512, 256, 0, stream>>>(sent, wWihs, wbss, xgq);
  k_srec<<<4, 512, 148992, stream>>>(wWs, h0f, c0f, h0b, c0b, xgq, outfb);
  k_tags<<<256, 256, 0, stream>>>(outfb, wWo, bo, (float*)d_out);
}

// Round 9
// 271.769 us; speedup vs baseline: 1.7038x; 1.1272x over previous
//
#include <hip/hip_runtime.h>
#include <cstdint>
#include <cstddef>

#define DI static __device__ __forceinline__

using half_t  = _Float16;
using half2_t = __attribute__((ext_vector_type(2))) _Float16;
using half8_t = __attribute__((ext_vector_type(8))) _Float16;
using f32x4_t = __attribute__((ext_vector_type(4))) float;

DI uint32_t pack2(float a, float b){ half2_t h; h[0]=(half_t)a; h[1]=(half_t)b; return __builtin_bit_cast(uint32_t,h); }
DI uint16_t f16b(float a){ return __builtin_bit_cast(uint16_t,(half_t)a); }
DI float lo16(uint32_t u){ half2_t h=__builtin_bit_cast(half2_t,u); return (float)h[0]; }
DI float hi16(uint32_t u){ half2_t h=__builtin_bit_cast(half2_t,u); return (float)h[1]; }
DI float fdot2(uint32_t w, uint32_t x, float acc){
  return __builtin_amdgcn_fdot2(__builtin_bit_cast(half2_t,w), __builtin_bit_cast(half2_t,x), acc, false);
}
DI float sigm(float x){ return __builtin_amdgcn_rcpf(1.f + __expf(-x)); }
DI float tanhf_(float x){ return 1.f - 2.f*__builtin_amdgcn_rcpf(__expf(2.f*x)+1.f); }

// problem sizes: B=32 S=64 NW=2048 T=198 L=50 WLEN=20 BERT=178 Hs=128 Hm=256 Din=306 O=32
#define SROW 308   // sentences_in row stride (306 used)
#define HSTR 280   // k_srec h-row stride in halves
#define ASTR 344   // k_sxg A-row stride in halves (688 B: 16B-aligned frags, 2-way banks)

// prep job sizes
#define N0 32768   // word Whh MFMA-B frags [ng512][kp64]
#define N1 16384   // word Wih MFMA-B frags [ng512][kp32] (k=50 zero-padded to 64)
#define N2 8192    // Wl B-frags [d128][kp64]
#define N3 512     // word bias sum [j128][g4]
#define N4 262144  // sent Whh B-frag layout [dir][ng1024][kp128], ng = w*128 + g*32 + jl
#define N5 327680  // sent Wih B-frag layout [dir][ng1024][kp160] (306 -> kp<153, rest 0)
#define N6 2048    // sent bias sum [dir][j256][g4]
#define N7 8192    // Wo f16x2 [kp256][o32]
#define NTOT (N0+N1+N2+N3+N4+N5+N6+N7)

__global__ void k_prep(const float* __restrict__ X,
                       const float* __restrict__ Wih_w, const float* __restrict__ Whh_w,
                       const float* __restrict__ bih_w, const float* __restrict__ bhh_w,
                       const float* __restrict__ Wl,
                       const float* __restrict__ Wih_f, const float* __restrict__ Whh_f,
                       const float* __restrict__ bih_f, const float* __restrict__ bhh_f,
                       const float* __restrict__ Wih_b, const float* __restrict__ Whh_b,
                       const float* __restrict__ bih_b, const float* __restrict__ bhh_b,
                       const float* __restrict__ Wo,
                       uint32_t* __restrict__ wWsw, uint32_t* __restrict__ wWxw,
                       uint32_t* __restrict__ wWlf, float* __restrict__ wbsw,
                       uint32_t* __restrict__ wWs, uint32_t* __restrict__ wWihs,
                       float* __restrict__ wbss, uint32_t* __restrict__ wWo)
{
  for (int i = blockIdx.x*blockDim.x + threadIdx.x; i < NTOT; i += gridDim.x*blockDim.x) {
    int id = i;
    if (id < N0) {                       // word Whh B-frags: ng = w*64+g*16+jl -> row g*128+w*16+jl
      int kp = id & 63, ng = id >> 6;
      int w = ng>>6, g = (ng>>4)&3, jl = ng&15;
      const float* s = Whh_w + (size_t)(g*128 + w*16 + jl)*128 + 2*kp;
      wWsw[id] = pack2(s[0], s[1]);
    } else if ((id -= N0) < N1) {        // word Wih B-frags, k padded 50->64
      int kp = id & 31, ng = id >> 5;
      int w = ng>>6, g = (ng>>4)&3, jl = ng&15;
      if (kp < 25) {
        const float* s = Wih_w + (size_t)(g*128 + w*16 + jl)*50 + 2*kp;
        wWxw[id] = pack2(s[0], s[1]);
      } else wWxw[id] = 0u;
    } else if ((id -= N1) < N2) {        // Wl B-frags [d][kp]
      int kp = id & 63, d = id >> 6;
      const float* s = Wl + (size_t)d*128 + 2*kp;
      wWlf[id] = pack2(s[0], s[1]);
    } else if ((id -= N2) < N3) {        // word bias sum [j][g]
      int g = id & 3, j = id>>2;
      wbsw[id] = bih_w[g*128+j] + bhh_w[g*128+j];
    } else if ((id -= N3) < N4) {        // sentence Whh: ng = w*128 + g*32 + jl -> row g*256+w*32+jl
      int kp = id & 127, ng = (id>>7)&1023, dir = id>>17;
      int w = ng>>7, g = (ng>>5)&3, jl = ng&31;
      int row = g*256 + w*32 + jl;
      const float* s = (dir ? Whh_b : Whh_f) + (size_t)row*256 + 2*kp;
      wWs[id] = pack2(s[0], s[1]);
    } else if ((id -= N4) < N5) {        // sentence Wih B-frags [dir][ng1024][kp160]
      int kp = id % 160; int q = id / 160;
      int ng = q & 1023, dir = q >> 10;
      int w = ng>>7, g = (ng>>5)&3, jl = ng&31;
      int row = g*256 + w*32 + jl;
      uint32_t v = 0u;
      if (kp < 153) {
        const float* s = (dir ? Wih_b : Wih_f) + (size_t)row*306 + 2*kp;
        v = pack2(s[0], s[1]);
      }
      wWihs[id] = v;
    } else if ((id -= N5) < N6) {        // sentence bias sums [dir][j][g]
      int g = id & 3, j = (id>>2)&255, dir = id>>10;
      int row = g*256+j;
      wbss[id] = dir ? (bih_b[row]+bhh_b[row]) : (bih_f[row]+bhh_f[row]);
    } else { id -= N6;                   // Wo packed [kp][o]
      int o = id & 31, kp = id>>5;
      const float* s = Wo + (size_t)o*512 + 2*kp;
      wWo[id] = pack2(s[0], s[1]);
    }
  }
}

// ---- word LSTM via MFMA: 128 blocks x 16 words, 8 waves, N=512 (wave: 16 j x 4 gates).
// Also extracts this block's bert columns into sent[:,128:306] (prologue, no extra sync).
__global__ __launch_bounds__(512, 2) void k_word(
    const float* __restrict__ X, const float* __restrict__ h0w, const float* __restrict__ c0w,
    const uint32_t* __restrict__ wWsw, const uint32_t* __restrict__ wWxw,
    const float* __restrict__ wbsw, const uint32_t* __restrict__ wWlf,
    const float* __restrict__ bl, float* __restrict__ sent)
{
  __shared__ __align__(16) uint32_t lets[11520];      // [t20][m16][36] f16x2 (72 cols, 50 real)
  __shared__ __align__(16) uint16_t hbuf[2][2176];    // [m16][136]
  const int tid = threadIdx.x;
  const int wave = tid >> 6, lane = tid & 63;
  const int l15 = lane & 15, l4 = lane >> 4;
  const int wg0 = blockIdx.x * 16;

  uint4 Bh[4][4], Bx[4][2];
  #pragma unroll
  for (int g = 0; g < 4; ++g) {
    int ng = wave*64 + g*16 + l15;
    #pragma unroll
    for (int Kt = 0; Kt < 4; ++Kt) Bh[g][Kt] = *(const uint4*)(wWsw + ng*64 + Kt*16 + l4*4);
    #pragma unroll
    for (int Kt = 0; Kt < 2; ++Kt) Bx[g][Kt] = *(const uint4*)(wWxw + ng*32 + Kt*16 + l4*4);
  }
  // bert: sent[wg, 128+ii] = Xw[wg, 20+ii, 0]
  for (int i = tid; i < 16*178; i += 512) {
    int m = i / 178, ii = i - m*178;
    sent[(size_t)(wg0+m)*SROW + 128 + ii] = X[(size_t)(wg0+m)*9900 + (20+ii)*50];
  }
  for (int i = tid; i < 11520; i += 512) {
    int c = i % 36, mt = i / 36; int m = mt & 15, t = mt >> 4;
    lets[i] = (c < 25) ? pack2(X[(size_t)(wg0+m)*9900 + t*50 + 2*c],
                               X[(size_t)(wg0+m)*9900 + t*50 + 2*c + 1]) : 0u;
  }
  for (int i = tid; i < 2048; i += 512) {
    int m = i >> 7, k = i & 127;
    hbuf[0][m*136 + k] = f16b(h0w[(size_t)(wg0+m)*128 + k]);
  }
  const float4 bs = *(const float4*)(wbsw + (wave*16 + l15)*4);
  float cr[4];
  #pragma unroll
  for (int r = 0; r < 4; ++r) cr[r] = c0w[(size_t)(wg0 + l4*4 + r)*128 + wave*16 + l15];
  __syncthreads();

  uint16_t* hc = hbuf[0];
  uint16_t* hn = hbuf[1];
  const uint16_t* lp = (const uint16_t*)lets;
  #pragma unroll 1
  for (int t = 0; t < 20; ++t) {
    f32x4_t acc[4];
    acc[0] = (f32x4_t){bs.x,bs.x,bs.x,bs.x};
    acc[1] = (f32x4_t){bs.y,bs.y,bs.y,bs.y};
    acc[2] = (f32x4_t){bs.z,bs.z,bs.z,bs.z};
    acc[3] = (f32x4_t){bs.w,bs.w,bs.w,bs.w};
    #pragma unroll
    for (int Kt = 0; Kt < 2; ++Kt) {
      uint4 av = *(const uint4*)(lp + (t*16 + l15)*72 + Kt*32 + l4*8);
      half8_t a = __builtin_bit_cast(half8_t, av);
      #pragma unroll
      for (int g = 0; g < 4; ++g)
        acc[g] = __builtin_amdgcn_mfma_f32_16x16x32_f16(a, __builtin_bit_cast(half8_t, Bx[g][Kt]), acc[g], 0,0,0);
    }
    #pragma unroll
    for (int Kt = 0; Kt < 4; ++Kt) {
      uint4 av = *(const uint4*)(hc + l15*136 + Kt*32 + l4*8);
      half8_t a = __builtin_bit_cast(half8_t, av);
      #pragma unroll
      for (int g = 0; g < 4; ++g)
        acc[g] = __builtin_amdgcn_mfma_f32_16x16x32_f16(a, __builtin_bit_cast(half8_t, Bh[g][Kt]), acc[g], 0,0,0);
    }
    #pragma unroll
    for (int r = 0; r < 4; ++r) {
      float cc = sigm(acc[1][r])*cr[r] + sigm(acc[0][r])*tanhf_(acc[2][r]);
      cr[r] = cc;
      float hh = sigm(acc[3][r])*tanhf_(cc);
      hn[(l4*4+r)*136 + wave*16 + l15] = f16b(hh);
    }
    uint16_t* tp = hc; hc = hn; hn = tp;
    __syncthreads();
  }
  uint4 Bl[4];
  #pragma unroll
  for (int Kt = 0; Kt < 4; ++Kt) Bl[Kt] = *(const uint4*)(wWlf + (wave*16 + l15)*64 + Kt*16 + l4*4);
  f32x4_t a2 = (f32x4_t){0.f,0.f,0.f,0.f};
  #pragma unroll
  for (int Kt = 0; Kt < 4; ++Kt) {
    uint4 av = *(const uint4*)(hc + l15*136 + Kt*32 + l4*8);
    a2 = __builtin_amdgcn_mfma_f32_16x16x32_f16(__builtin_bit_cast(half8_t, av),
                                                __builtin_bit_cast(half8_t, Bl[Kt]), a2, 0,0,0);
  }
  const float blv = bl[wave*16 + l15];
  #pragma unroll
  for (int r = 0; r < 4; ++r)
    sent[(size_t)(wg0 + l4*4 + r)*SROW + wave*16 + l15] = a2[r] + blv;
}

// ---- sentence xg GEMM via MFMA: 128 blocks = (dir, tt). M=32 (all b), 8 waves x N=128.
// A = sent rows (b*64+si) f16 in LDS; B = wWihs frags (same verified layout family as Whh).
// Output layout identical to R4-verified xgq.
__global__ __launch_bounds__(512) void k_sxg(
    const float* __restrict__ sent, const uint32_t* __restrict__ Wihs,
    const float* __restrict__ bss, uint2* __restrict__ xgq)
{
  __shared__ __align__(16) uint16_t xs[32*ASTR];
  const int tid = threadIdx.x;
  const int wave = tid >> 6, lane = tid & 63;
  const int l15 = lane & 15, l4 = lane >> 4;
  const int dir = blockIdx.x >> 6, tt = blockIdx.x & 63;
  const int si = dir ? (63 - tt) : tt;

  // stage A: 32 rows x 320 cols f16 (306 real, rest 0)
  for (int i = tid; i < 32*160; i += 512) {
    int kp = i % 160, b = i / 160;
    uint32_t v = 0u;
    if (kp < 153) {
      const float* s = sent + (size_t)(b*64 + si)*SROW + 2*kp;
      v = pack2(s[0], s[1]);
    }
    *(uint32_t*)(xs + b*ASTR + 2*kp) = v;
  }
  __syncthreads();

  f32x4_t acc[2][8];
  #pragma unroll
  for (int Nt = 0; Nt < 8; ++Nt) {                  // Nt = g*2 + jh
    int g = Nt >> 1, jh = Nt & 1;
    float bv = bss[(dir*256 + wave*32 + jh*16 + l15)*4 + g];
    acc[0][Nt] = (f32x4_t){bv,bv,bv,bv};
    acc[1][Nt] = (f32x4_t){bv,bv,bv,bv};
  }
  const uint32_t* Bb = Wihs + (size_t)(dir*1024 + wave*128)*160 + l15*160 + l4*4;
  #pragma unroll
  for (int Kt = 0; Kt < 10; ++Kt) {
    uint4 av0 = *(const uint4*)(xs + l15*ASTR + Kt*32 + l4*8);
    uint4 av1 = *(const uint4*)(xs + (16 + l15)*ASTR + Kt*32 + l4*8);
    half8_t a0 = __builtin_bit_cast(half8_t, av0);
    half8_t a1 = __builtin_bit_cast(half8_t, av1);
    #pragma unroll
    for (int Nt = 0; Nt < 8; ++Nt) {
      uint4 bv = *(const uint4*)(Bb + (size_t)Nt*16*160 + Kt*16);
      half8_t b = __builtin_bit_cast(half8_t, bv);
      acc[0][Nt] = __builtin_amdgcn_mfma_f32_16x16x32_f16(a0, b, acc[0][Nt], 0,0,0);
      acc[1][Nt] = __builtin_amdgcn_mfma_f32_16x16x32_f16(a1, b, acc[1][Nt], 0,0,0);
    }
  }
  #pragma unroll
  for (int Mt = 0; Mt < 2; ++Mt)
    #pragma unroll
    for (int jh = 0; jh < 2; ++jh)
      #pragma unroll
      for (int r = 0; r < 4; ++r) {
        uint2 v;
        v.x = pack2(acc[Mt][0+jh][r], acc[Mt][2+jh][r]);   // {i, f}
        v.y = pack2(acc[Mt][4+jh][r], acc[Mt][6+jh][r]);   // {g, o}
        size_t idx = ((((size_t)(dir*64 + tt)*2 + Mt)*8 + wave)*2 + jh)*256 + l15*16 + l4*4 + r;
        xgq[idx] = v;
      }
}

// ---- sentence recurrence: unchanged from R8 (best measured: 193 us)
__global__ __launch_bounds__(512, 2) void k_srec(
    const uint32_t* __restrict__ Ws, const float* __restrict__ h0f, const float* __restrict__ c0f,
    const float* __restrict__ h0b, const float* __restrict__ c0b,
    const uint2* __restrict__ xgq, uint16_t* __restrict__ outfb)
{
  extern __shared__ char smem[];               // [0,131072) B-frags, then h dbuf 2x[16][HSTR]
  uint16_t* h16a = (uint16_t*)(smem + 131072);
  uint16_t* h16b = h16a + 16*HSTR;
  const int tid = threadIdx.x;
  const int wave = tid >> 6, lane = tid & 63;
  const int dir = blockIdx.x >> 1, half = blockIdx.x & 1, m0 = half * 16;
  const int l15 = lane & 15, l4 = lane >> 4;

  uint4 Breg[8][6];
  #pragma unroll
  for (int Nt = 0; Nt < 8; ++Nt) {
    #pragma unroll
    for (int Kt = 0; Kt < 8; ++Kt) {
      int ng = wave*128 + Nt*16 + l15;
      uint4 v = *(const uint4*)(Ws + (size_t)(dir*1024 + ng)*128 + Kt*16 + l4*4);
      if (Kt < 6) Breg[Nt][Kt] = v;
      else *(uint4*)(smem + (((wave*16 + Nt*2 + (Kt-6))*64 + lane)*16)) = v;
    }
  }
  {
    const float* h0 = dir ? h0b : h0f;
    for (int i = tid; i < 16*256; i += 512) {
      int m = i >> 8, k = i & 255;
      h16a[m*HSTR + k] = f16b(h0[(size_t)(m0+m)*256 + k]);
    }
  }
  float cr[2][4];
  {
    const float* c0 = dir ? c0b : c0f;
    #pragma unroll
    for (int jh = 0; jh < 2; ++jh)
      #pragma unroll
      for (int r = 0; r < 4; ++r)
        cr[jh][r] = c0[(size_t)(m0 + l4*4 + r)*256 + wave*32 + jh*16 + l15];
  }
  __syncthreads();

  const char* xbase = (const char*)xgq + (size_t)dir*4194304 + half*32768;
  const uint32_t xlane = wave*4096 + l15*128 + l4*32;
  const int s0 = dir ? 63 : 0;
  const int sdelta = dir ? -65536 : 65536;
  const char* obase = (const char*)outfb + (size_t)s0*65536 + half*32768 + dir*16384;
  const uint32_t olane = (l4*4)*512 + wave*64 + l15*2;
  const uint32_t aoff = l15*HSTR + l4*8;

  uint16_t* hc = h16a;
  uint16_t* hn = h16b;

#define UPD1(JH, R, GI, GF, GG, GO) {                                         \
    float eo = __expf(-(GO));                                                 \
    float ef = __expf(-(GF)), ei = __expf(-(GI)), eg = __expf(-2.f*(GG));     \
    float pef = 1.f + ef, pei = 1.f + ei, peg = 1.f + eg;                     \
    float num = cr[JH][R]*pei*peg + (1.f - eg)*pef;                           \
    float cc  = num * __builtin_amdgcn_rcpf(pef*pei*peg);                     \
    cr[JH][R] = cc;                                                           \
    float ec = __expf(-2.f*cc);                                               \
    float hh = (1.f - ec) * __builtin_amdgcn_rcpf((1.f + ec)*(1.f + eo));     \
    uint16_t hb = f16b(hh);                                                   \
    hn[(l4*4+(R))*HSTR + wave*32 + (JH)*16 + l15] = hb;                       \
    *(uint16_t*)(obase + olane + (R)*512 + (JH)*32) = hb;                     \
  }

  uint4 p0 = *(const uint4*)(xbase + xlane);
  uint4 p1 = *(const uint4*)(xbase + xlane + 16);
  uint4 p2 = *(const uint4*)(xbase + xlane + 2048);
  uint4 p3 = *(const uint4*)(xbase + xlane + 2064);

  #pragma unroll 1
  for (int t = 0; t < 64; ++t) {
    f32x4_t acc[8];
    acc[0] = (f32x4_t){lo16(p0.x), lo16(p0.z), lo16(p1.x), lo16(p1.z)};
    acc[2] = (f32x4_t){hi16(p0.x), hi16(p0.z), hi16(p1.x), hi16(p1.z)};
    acc[4] = (f32x4_t){lo16(p0.y), lo16(p0.w), lo16(p1.y), lo16(p1.w)};
    acc[6] = (f32x4_t){hi16(p0.y), hi16(p0.w), hi16(p1.y), hi16(p1.w)};
    acc[1] = (f32x4_t){lo16(p2.x), lo16(p2.z), lo16(p3.x), lo16(p3.z)};
    acc[3] = (f32x4_t){hi16(p2.x), hi16(p2.z), hi16(p3.x), hi16(p3.z)};
    acc[5] = (f32x4_t){lo16(p2.y), lo16(p2.w), lo16(p3.y), lo16(p3.w)};
    acc[7] = (f32x4_t){hi16(p2.y), hi16(p2.w), hi16(p3.y), hi16(p3.w)};

    __builtin_amdgcn_s_setprio(1);
    #pragma unroll
    for (int Kt = 0; Kt < 8; ++Kt) {
      uint4 av = *(const uint4*)(hc + aoff + Kt*32);
      half8_t a = __builtin_bit_cast(half8_t, av);
      #pragma unroll
      for (int g = 0; g < 4; ++g) {
        const int Nt = g*2;
        uint4 bv;
        if (Kt < 6) bv = Breg[Nt][Kt];
        else bv = *(const uint4*)(smem + (((wave*16 + Nt*2 + (Kt-6))*64 + lane)*16));
        acc[Nt] = __builtin_amdgcn_mfma_f32_16x16x32_f16(a, __builtin_bit_cast(half8_t, bv), acc[Nt], 0,0,0);
      }
    }
    __builtin_amdgcn_s_setprio(0);

    #pragma unroll
    for (int Kt = 0; Kt < 8; ++Kt) {
      uint4 av = *(const uint4*)(hc + aoff + Kt*32);
      half8_t a = __builtin_bit_cast(half8_t, av);
      #pragma unroll
      for (int g = 0; g < 4; ++g) {
        const int Nt = g*2 + 1;
        uint4 bv;
        if (Kt < 6) bv = Breg[Nt][Kt];
        else bv = *(const uint4*)(smem + (((wave*16 + Nt*2 + (Kt-6))*64 + lane)*16));
        acc[Nt] = __builtin_amdgcn_mfma_f32_16x16x32_f16(a, __builtin_bit_cast(half8_t, bv), acc[Nt], 0,0,0);
      }
      if (Kt & 1) {
        const int r = Kt >> 1;
        UPD1(0, r, acc[0][r], acc[2][r], acc[4][r], acc[6][r]);
        __builtin_amdgcn_sched_group_barrier(0x008, 8, 0);
        __builtin_amdgcn_sched_group_barrier(0x002, 44, 0);
      }
    }

    p0 = *(const uint4*)(xbase + xlane + 65536);
    p1 = *(const uint4*)(xbase + xlane + 65536 + 16);
    p2 = *(const uint4*)(xbase + xlane + 65536 + 2048);
    p3 = *(const uint4*)(xbase + xlane + 65536 + 2064);

    #pragma unroll
    for (int r = 0; r < 4; ++r)
      UPD1(1, r, acc[1][r], acc[3][r], acc[5][r], acc[7][r]);

    { uint16_t* tp = hc; hc = hn; hn = tp; }
    xbase += 65536;
    obase += sdelta;
    asm volatile("s_waitcnt lgkmcnt(0)\ns_barrier" ::: "memory");
  }
#undef UPD1
}

// ---- tags + softmax (reads the R4-verified outfb layout)
__global__ __launch_bounds__(256) void k_tags(
    const uint16_t* __restrict__ outfb, const uint32_t* __restrict__ Wo16,
    const float* __restrict__ bo, float* __restrict__ out)
{
  __shared__ uint32_t xr[8*256];
  const int tid = threadIdx.x;
  const int w0 = blockIdx.x * 8;
  const uint32_t* src = (const uint32_t*)outfb;
  for (int i = tid; i < 2048; i += 256) {
    int w = i >> 8, kp = i & 255;
    int widx = w0 + w;
    int s = widx & 63, q = widx >> 6;
    int half = q >> 4, m = q & 15;
    int dir = kp >> 7, wv = (kp >> 4) & 7, jh = (kp >> 3) & 1, l15h = kp & 7;
    xr[i] = src[s*16384 + half*8192 + dir*4096 + m*128 + wv*16 + jh*8 + l15h];
  }
  __syncthreads();
  const int o = tid & 31, w = tid >> 5;
  float a = bo[o];
  for (int kp = 0; kp < 256; ++kp)
    a = fdot2(Wo16[kp*32 + o], xr[w*256 + kp], a);
  float mx = a;
  #pragma unroll
  for (int off = 16; off; off >>= 1) mx = fmaxf(mx, __shfl_xor(mx, off, 32));
  float e = __expf(a - mx);
  float ssum = e;
  #pragma unroll
  for (int off = 16; off; off >>= 1) ssum += __shfl_xor(ssum, off, 32);
  out[(size_t)(w0+w)*32 + o] = e * __builtin_amdgcn_rcpf(ssum);
}

extern "C" void kernel_launch(void* const* d_in, const int* in_sizes, int n_in,
                              void* d_out, int out_size, void* d_ws, size_t ws_size,
                              hipStream_t stream) {
  const float* X     = (const float*)d_in[0];
  const float* h0w   = (const float*)d_in[1];
  const float* c0w   = (const float*)d_in[2];
  const float* h0f   = (const float*)d_in[3];
  const float* c0f   = (const float*)d_in[4];
  const float* h0b   = (const float*)d_in[5];
  const float* c0b   = (const float*)d_in[6];
  const float* Wih_w = (const float*)d_in[7];
  const float* Whh_w = (const float*)d_in[8];
  const float* bih_w = (const float*)d_in[9];
  const float* bhh_w = (const float*)d_in[10];
  const float* Wl    = (const float*)d_in[11];
  const float* bl    = (const float*)d_in[12];
  const float* Wih_f = (const float*)d_in[13];
  const float* Whh_f = (const float*)d_in[14];
  const float* bih_f = (const float*)d_in[15];
  const float* bhh_f = (const float*)d_in[16];
  const float* Wih_b = (const float*)d_in[17];
  const float* Whh_b = (const float*)d_in[18];
  const float* bih_b = (const float*)d_in[19];
  const float* bhh_b = (const float*)d_in[20];
  const float* Wo    = (const float*)d_in[21];
  const float* bo    = (const float*)d_in[22];

  char* ws = (char*)d_ws;
  uint32_t* wWsw  = (uint32_t*)(ws + 0);          // 131072 B
  uint32_t* wWxw  = (uint32_t*)(ws + 131072);     // 65536 B
  uint32_t* wWlf  = (uint32_t*)(ws + 196608);     // 32768 B
  float*    wbsw  = (float*)   (ws + 229376);     // 2048 B
  uint32_t* wWs   = (uint32_t*)(ws + 231424);     // 1048576 B
  uint32_t* wWihs = (uint32_t*)(ws + 1280000);    // 1310720 B
  float*    wbss  = (float*)   (ws + 2590720);    // 8192 B
  uint32_t* wWo   = (uint32_t*)(ws + 2598912);    // 32768 B
  float*    sent  = (float*)   (ws + 2631680);    // 2523136 B
  uint2*    xgq   = (uint2*)   (ws + 5160960);    // 8388608 B
  uint16_t* outfb = (uint16_t*)(ws + 13549568);   // 2097152 B -> end ~15.6 MB

  hipFuncSetAttribute((const void*)k_srec, hipFuncAttributeMaxDynamicSharedMemorySize, 148992);

  k_prep<<<1024, 256, 0, stream>>>(X, Wih_w, Whh_w, bih_w, bhh_w, Wl, Wih_f, Whh_f, bih_f, bhh_f,
                                   Wih_b, Whh_b, bih_b, bhh_b, Wo,
                                   wWsw, wWxw, wWlf, wbsw, wWs, wWihs, wbss, wWo);
  k_word<<<128, 512, 0, stream>>>(X, h0w, c0w, wWsw, wWxw, wbsw, wWlf, bl, sent);
  k_sxg<<<128, 512, 0, stream>>>(sent, wWihs, wbss, xgq);
  k_srec<<<4, 512, 148992, stream>>>(wWs, h0f, c0f, h0b, c0b, xgq, outfb);
  k_tags<<<256, 256, 0, stream>>>(outfb, wWo, bo, (float*)d_out);
}